// Round 1
// baseline (200.433 us; speedup 1.0000x reference)
//
#include <hip/hip_runtime.h>
#include <hip/hip_bf16.h>
#include <stdint.h>

// MetaAttention: x[8,1024,768] f32, Wq/Wk/Wv/Wo[768,768] f32 -> out[8,1024,768] f32
// Pipeline (4 kernels):
//   convert: x->xb, [Wq;Wk;Wv]->wqkv (d_out head scratch), Wo->wob (d_ws tail).
//   gemm_qkv: fused NT GEMM M=8192 N=2304 K=768. NEW: 256x256 tile, BK=64,
//             8 waves (2Mx4N), 8-phase deep-pipelined schedule (T3+T4 counted
//             vmcnt(6), T5 setprio, T2 XOR swizzle, T1 XCD swizzle over 288
//             blocks). 128 KiB LDS double-buffered (2 K-tiles in flight).
//             q pre-scaled by 0.125*log2(e); v stored per-head transposed vt.
//   attn: (b,h) x 64 q-rows per block (grid 1536, XCD remap); BJ=128 K/V tiles.
//   gemm_out: out = vect Wo^T, 64x128 tile (768 blocks), pure glds.
// d_ws (bf16): q/vect | k | vt | wob.

typedef __bf16 bf16x8 __attribute__((ext_vector_type(8)));
typedef __bf16 bf16x4 __attribute__((ext_vector_type(4)));
typedef float f32x4 __attribute__((ext_vector_type(4)));

#define GAS __attribute__((address_space(1)))
#define LAS __attribute__((address_space(3)))

__device__ __forceinline__ void glds16(const short* gp, short* lp) {
  __builtin_amdgcn_global_load_lds((const GAS void*)gp, (LAS void*)lp, 16, 0, 0);
}

__device__ __forceinline__ float fast_exp2(float x) {
#if __has_builtin(__builtin_amdgcn_exp2f)
  return __builtin_amdgcn_exp2f(x);
#else
  return __expf(x * 0.6931471805599453f);
#endif
}

__device__ __forceinline__ short bfbits(float f) {
  __bf16 b = (__bf16)f;                  // fptrunc RNE -> HW cvt
  union { __bf16 b; short s; } cv; cv.b = b;
  return cv.s;
}

__device__ __forceinline__ void stage8_f32(const float* __restrict__ src, short* dst) {
  float4 f0 = ((const float4*)src)[0];
  float4 f1 = ((const float4*)src)[1];
  bf16x8 t;
  t[0] = (__bf16)f0.x; t[1] = (__bf16)f0.y; t[2] = (__bf16)f0.z; t[3] = (__bf16)f0.w;
  t[4] = (__bf16)f1.x; t[5] = (__bf16)f1.y; t[6] = (__bf16)f1.z; t[7] = (__bf16)f1.w;
  *(bf16x8*)dst = t;
}

// --------------------------------------------------------------------------
// fp32 -> bf16 bulk conversion, flat exact grid: 1056 blocks x 1024 units.
// --------------------------------------------------------------------------
__global__ __launch_bounds__(256) void convert_kernel(
    const float* __restrict__ x, const float* __restrict__ Wq,
    const float* __restrict__ Wk, const float* __restrict__ Wv,
    const float* __restrict__ Wo,
    short* __restrict__ xb, short* __restrict__ wqkv, short* __restrict__ wob) {
  int u0 = blockIdx.x * 1024 + threadIdx.x;
#pragma unroll
  for (int i = 0; i < 4; ++i) {
    int u = u0 + i * 256;
    const float* src; short* dst;
    if (u < 786432) { src = x + (size_t)u * 8; dst = xb + (size_t)u * 8; }
    else if (u < 1007616) {
      int r = u - 786432;
      int wsel = r / 73728, off = r % 73728;
      const float* W = (wsel == 0) ? Wq : (wsel == 1) ? Wk : Wv;
      src = W + (size_t)off * 8;
      dst = wqkv + (size_t)r * 8;
    } else {
      int r = u - 1007616;
      src = Wo + (size_t)r * 8; dst = wob + (size_t)r * 8;
    }
    stage8_f32(src, dst);
  }
}

// --------------------------------------------------------------------------
// 8-phase helpers for gemm_qkv
// --------------------------------------------------------------------------
// Stage one 128x64 bf16 half-tile (16 KB): 1024 16B chunks, 2/thread @512thr.
// LDS dest linear in lane order (glds requirement); global source column
// pre-swizzled (chunk c of row r fetched from column (c ^ (r&7))*8) so the
// swizzled ds_read below sees conflict-free layout.
__device__ __forceinline__ void stage_half(const short* __restrict__ g, short* l,
                                           int w, int lane) {
#pragma unroll
  for (int p = 0; p < 2; ++p) {
    int c = (w * 2 + p) * 64 + lane;
    int row = c >> 3;
    int cs = ((c & 7) ^ (row & 7)) * 8;
    glds16(g + (size_t)row * 768 + cs, l + c * 8);
  }
}

__device__ __forceinline__ void bar_fence() {
  asm volatile("" ::: "memory");
  __builtin_amdgcn_s_barrier();
  asm volatile("" ::: "memory");
}

__device__ __forceinline__ void load_a8(const short* base, int wr, int l16, int quad,
                                        bf16x8 (&fa)[4][2]) {
#pragma unroll
  for (int mf = 0; mf < 4; ++mf)
#pragma unroll
    for (int kk = 0; kk < 2; ++kk) {
      int row = wr * 64 + mf * 16 + l16;
      fa[mf][kk] = *(const bf16x8*)&base[row * 64 + ((((kk << 2) + quad) ^ (row & 7)) << 3)];
    }
}

__device__ __forceinline__ void load_b4(const short* base, int rbase, int l16, int quad,
                                        bf16x8 (&fb)[2][2]) {
#pragma unroll
  for (int nf = 0; nf < 2; ++nf)
#pragma unroll
    for (int kk = 0; kk < 2; ++kk) {
      int row = rbase + nf * 16 + l16;
      fb[nf][kk] = *(const bf16x8*)&base[row * 64 + ((((kk << 2) + quad) ^ (row & 7)) << 3)];
    }
}

__device__ __forceinline__ void mma16(const bf16x8 (&fa)[4][2], const bf16x8 (&fb)[2][2],
                                      f32x4 (&acc)[4][4], int nf0) {
  __builtin_amdgcn_s_setprio(1);
#pragma unroll
  for (int kk = 0; kk < 2; ++kk)
#pragma unroll
    for (int mf = 0; mf < 4; ++mf)
#pragma unroll
      for (int nf = 0; nf < 2; ++nf)
        acc[mf][nf0 + nf] = __builtin_amdgcn_mfma_f32_16x16x32_bf16(
            fa[mf][kk], fb[nf][kk], acc[mf][nf0 + nf], 0, 0, 0);
  __builtin_amdgcn_s_setprio(0);
}

// --------------------------------------------------------------------------
// Fused QKV NT GEMM, 256x256 tile, BK=64, 8-phase pipelined schedule.
//
// Geometry: 8 waves 2Mx4N, per-wave output 128(rows: 2 halves x 64)x64(cols).
// LDS [kbuf][A|B][half][128*64] = 128 KiB, 2 K-tiles in flight.
//
// Per iteration (K-tiles 2i in buf0, 2i+1 in buf1), phase -> {reads, MFMA
// quadrant, half-tile staged}:
//   ph1: rd A0,Bn0   Q(0,0)  stage buf1.A1(t=2i+1)   [A1 region dead since prev ph7]
//   ph2: rd Bn1      Q(0,1)  stage buf0.A0(t+2)      [A0 read in ph1]
//   ph3: rd A1       Q(1,1)  stage buf0.B0(t+2)      [B rows 0-127 read ph1+ph2]
//   ph4:             Q(1,0)  stage buf0.B1(t+2); vmcnt(6)  -> buf1 t=2i+1 fully landed
//   ph5: rd A0,Bn0   Q(0,0)  stage buf0.A1(t+2)
//   ph6: rd Bn1      Q(0,1)  stage buf1.A0(t+3)
//   ph7: rd A1       Q(1,1)  stage buf1.B0(t+3)
//   ph8:             Q(1,0)  stage buf1.B1(t+3); vmcnt(6)  -> buf0 t+2 fully landed
// vmcnt(6) = 3 half-tiles (2 loads each) in flight; never drained to 0 except
// last iteration's ph4 (its prefetches are skipped, so counted-wait is short).
// --------------------------------------------------------------------------
__global__ __launch_bounds__(512, 2) void gemm_qkv(
    const short* __restrict__ xb, const short* __restrict__ wqkv,
    short* __restrict__ q, short* __restrict__ k, short* __restrict__ vt) {
  const int lin = blockIdx.x;
  const int swz = (lin & 7) * 36 + (lin >> 3);   // 288 % 8 == 0 -> bijective XCD swizzle
  const int bx = swz & 31;                       // M tile (32)
  const int by = swz >> 5;                       // N tile (9); runs share B panel
  const int m0 = bx * 256;
  const int n0g = by * 256;
  const int tid = threadIdx.x;
  const int w = tid >> 6, lane = tid & 63, l16 = lane & 15, quad = lane >> 4;
  const int wr = w >> 2, wc = w & 3;

  __shared__ short lds[2][2][2][8192];  // [kbuf][0=A,1=B][half][128*64]

  const short* Asrc = xb + (size_t)m0 * 768;
  const short* Bsrc = wqkv + (size_t)n0g * 768;

  f32x4 acc[2][4][4];  // [Mhalf][mf][nf]
#pragma unroll
  for (int h = 0; h < 2; ++h)
#pragma unroll
    for (int i = 0; i < 4; ++i)
#pragma unroll
      for (int j = 0; j < 4; ++j) acc[h][i][j] = (f32x4){0.f, 0.f, 0.f, 0.f};

  // prologue: tile0 {A0,B0,B1,A1} (8 loads) + tile1 {A0,B0,B1} (6 loads);
  // vmcnt(6) -> tile0's 8 landed (FIFO), tile1's 3 halves stay in flight.
  stage_half(Asrc, &lds[0][0][0][0], w, lane);
  stage_half(Bsrc, &lds[0][1][0][0], w, lane);
  stage_half(Bsrc + 98304, &lds[0][1][1][0], w, lane);
  stage_half(Asrc + 98304, &lds[0][0][1][0], w, lane);
  stage_half(Asrc + 64, &lds[1][0][0][0], w, lane);
  stage_half(Bsrc + 64, &lds[1][1][0][0], w, lane);
  stage_half(Bsrc + 98304 + 64, &lds[1][1][1][0], w, lane);
  asm volatile("s_waitcnt vmcnt(6)" ::: "memory");
  bar_fence();

  const int bh = wc >> 1;               // which 128-row staging half holds this wave's B band
  const int rb0 = (wc & 1) * 64;        // row base within that half
  const short* bb0 = &lds[0][1][bh][0];
  const short* bb1 = &lds[1][1][bh][0];

  bf16x8 fa[4][2], fb0[2][2], fb1[2][2];

  for (int i = 0; i < 6; ++i) {
    const int t1 = 2 * i + 1, t2 = 2 * i + 2, t3 = 2 * i + 3;
    const bool pf = (i < 5);  // prefetch valid (tiles t2,t3 < 12)

    // ===== K-tile 2i (buf0) =====
    // ph1
    load_a8(&lds[0][0][0][0], wr, l16, quad, fa);
    load_b4(bb0, rb0, l16, quad, fb0);
    stage_half(Asrc + 98304 + (size_t)t1 * 64, &lds[1][0][1][0], w, lane);
    bar_fence();
    mma16(fa, fb0, acc[0], 0);
    bar_fence();
    // ph2
    load_b4(bb0, rb0 + 32, l16, quad, fb1);
    if (pf) stage_half(Asrc + (size_t)t2 * 64, &lds[0][0][0][0], w, lane);
    bar_fence();
    mma16(fa, fb1, acc[0], 2);
    bar_fence();
    // ph3
    load_a8(&lds[0][0][1][0], wr, l16, quad, fa);
    if (pf) stage_half(Bsrc + (size_t)t2 * 64, &lds[0][1][0][0], w, lane);
    bar_fence();
    mma16(fa, fb1, acc[1], 2);
    bar_fence();
    // ph4
    if (pf) {
      stage_half(Bsrc + 98304 + (size_t)t2 * 64, &lds[0][1][1][0], w, lane);
      asm volatile("s_waitcnt vmcnt(6)" ::: "memory");
    } else {
      asm volatile("s_waitcnt vmcnt(0)" ::: "memory");  // tail: drain (prefetches skipped)
    }
    bar_fence();
    mma16(fa, fb0, acc[1], 0);
    bar_fence();

    // ===== K-tile 2i+1 (buf1) =====
    // ph5
    load_a8(&lds[1][0][0][0], wr, l16, quad, fa);
    load_b4(bb1, rb0, l16, quad, fb0);
    if (pf) stage_half(Asrc + 98304 + (size_t)t2 * 64, &lds[0][0][1][0], w, lane);
    bar_fence();
    mma16(fa, fb0, acc[0], 0);
    bar_fence();
    // ph6
    load_b4(bb1, rb0 + 32, l16, quad, fb1);
    if (pf) stage_half(Asrc + (size_t)t3 * 64, &lds[1][0][0][0], w, lane);
    bar_fence();
    mma16(fa, fb1, acc[0], 2);
    bar_fence();
    // ph7
    load_a8(&lds[1][0][1][0], wr, l16, quad, fa);
    if (pf) stage_half(Bsrc + (size_t)t3 * 64, &lds[1][1][0][0], w, lane);
    bar_fence();
    mma16(fa, fb1, acc[1], 2);
    bar_fence();
    // ph8
    if (pf) stage_half(Bsrc + 98304 + (size_t)t3 * 64, &lds[1][1][1][0], w, lane);
    asm volatile("s_waitcnt vmcnt(6)" ::: "memory");
    bar_fence();
    mma16(fa, fb0, acc[1], 0);
    bar_fence();
  }

  // epilogue: same index convention as round-7 kernel (verified), remapped to
  // 256-wide tiles: rows m0 + h*128 + wr*64 + mf*16 + quad*4 + r, cols
  // nl0 + nf*16 + l16 with nl0 = (by%3)*256 + wc*64.
  const int wsel = by / 3;                    // 0:q 1:k 2:v
  const int nl0 = (by % 3) * 256 + wc * 64;
  if (wsel == 2) {
#pragma unroll
    for (int h = 0; h < 2; ++h)
#pragma unroll
      for (int mf = 0; mf < 4; ++mf)
#pragma unroll
        for (int nf = 0; nf < 4; ++nf) {
          int token = m0 + h * 128 + wr * 64 + mf * 16 + quad * 4;  // +r contiguous
          int nl = nl0 + nf * 16 + l16;
          int bhh = (token >> 10) * 12 + (nl >> 6);
          short tmp[4];
#pragma unroll
          for (int r = 0; r < 4; ++r) tmp[r] = bfbits(acc[h][mf][nf][r]);
          *(uint2*)(vt + (size_t)bhh * 65536 + (size_t)(nl & 63) * 1024 + (token & 1023)) =
              *(const uint2*)tmp;
        }
  } else {
    short* C = wsel ? k : q;
    const float sc = wsel ? 1.0f : 0.1803368801111244f;  // q: 0.125*log2(e)
#pragma unroll
    for (int h = 0; h < 2; ++h)
#pragma unroll
      for (int mf = 0; mf < 4; ++mf)
#pragma unroll
        for (int nf = 0; nf < 4; ++nf)
#pragma unroll
          for (int r = 0; r < 4; ++r) {
            int row = m0 + h * 128 + wr * 64 + mf * 16 + quad * 4 + r;
            int nl = nl0 + nf * 16 + l16;
            C[(size_t)row * 768 + nl] = bfbits(acc[h][mf][nf][r] * sc);
          }
  }
}

// --------------------------------------------------------------------------
// Flash attention: block = (b,h) x 64 q-rows, grid 1536 (XCD remap: idx%96=bh).
// BJ=128: per barrier-pair stage K[128x64] + V^T[64x128]; two 64-col compute
// halves reuse s[] regs. Q staged into sK space (frags->regs). LDS 32KB.
// S' = K Q'^T; P = exp2(S') in regs; paired-tile PV. vect aliases q.
// --------------------------------------------------------------------------
__global__ __launch_bounds__(256) void attn_kernel(
    const short* __restrict__ q, const short* __restrict__ k,
    const short* __restrict__ vt, short* __restrict__ vect) {
  const int bh = blockIdx.x % 96;
  const int qt = blockIdx.x / 96;
  const int b = bh / 12, h = bh % 12;
  const int m0 = qt * 64;
  const int tid = threadIdx.x;
  const int w = tid >> 6, lane = tid & 63, l16 = lane & 15, quad = lane >> 4;

  __shared__ short sK[128 * 64];   // K tile; also hosts Q during prologue
  __shared__ short sVt[64 * 128];  // V^T tile [d][j], 16 chunks/row

  const size_t base = (size_t)b * 786432 + (size_t)h * 64;
  const size_t vbase = (size_t)bh * 65536;

  // prologue: stage Q (64x64) into sK head, hoist fragments to registers
#pragma unroll
  for (int p = 0; p < 2; ++p) {
    int lin = (w * 2 + p) * 64 + lane;
    int row = lin >> 3;
    int cs = ((lin & 7) ^ (row & 7)) * 8;
    glds16(q + base + (size_t)(m0 + row) * 768 + cs, &sK[lin * 8]);
  }
  __syncthreads();
  bf16x8 bq[2];
#pragma unroll
  for (int kk = 0; kk < 2; ++kk) {
    int row = w * 16 + l16;
    bq[kk] = *(const bf16x8*)&sK[row * 64 + (((kk * 4 + quad) ^ (row & 7)) << 3)];
  }

  f32x4 l4 = (f32x4){0.f, 0.f, 0.f, 0.f};
  f32x4 oacc[4];
#pragma unroll
  for (int td = 0; td < 4; ++td) oacc[td] = (f32x4){0.f, 0.f, 0.f, 0.f};

  for (int j0 = 0; j0 < 1024; j0 += 128) {
    __syncthreads();  // prior reads retired (incl. bq prologue reads on iter 0)
    // stage K: 128 rows x 64 cols, 1024 chunks (4/thread), 8-chunk rows
#pragma unroll
    for (int p = 0; p < 4; ++p) {
      int lin = (w * 4 + p) * 64 + lane;
      int row = lin >> 3;
      int cs = ((lin & 7) ^ (row & 7)) * 8;
      glds16(k + base + (size_t)(j0 + row) * 768 + cs, &sK[lin * 8]);
    }
    // stage V^T: 64 rows x 128 cols, 1024 chunks (4/thread), 16-chunk rows
#pragma unroll
    for (int p = 0; p < 4; ++p) {
      int lin = (w * 4 + p) * 64 + lane;
      int row = lin >> 4;
      int c = lin & 15;
      int cs = (c ^ (row & 15)) * 8;
      glds16(vt + vbase + (size_t)row * 1024 + j0 + cs, &sVt[lin * 8]);
    }
    __syncthreads();

#pragma unroll
    for (int jh = 0; jh < 2; ++jh) {
      // S' tiles: rows j = jh*64 + ti*16 + quad*4+r, col i=l16
      f32x4 s[4];
#pragma unroll
      for (int ti = 0; ti < 4; ++ti) s[ti] = (f32x4){0.f, 0.f, 0.f, 0.f};
#pragma unroll
      for (int kk = 0; kk < 2; ++kk)
#pragma unroll
        for (int ti = 0; ti < 4; ++ti) {
          int row = jh * 64 + ti * 16 + l16;
          bf16x8 a = *(const bf16x8*)&sK[row * 64 + (((kk * 4 + quad) ^ (row & 7)) << 3)];
          s[ti] = __builtin_amdgcn_mfma_f32_16x16x32_bf16(a, bq[kk], s[ti], 0, 0, 0);
        }

      // P = exp2(S'); packed row-sum; HW packed bf16 convert
      bf16x4 pb[4];
#pragma unroll
      for (int ti = 0; ti < 4; ++ti) {
        f32x4 e;
        e[0] = fast_exp2(s[ti][0]);
        e[1] = fast_exp2(s[ti][1]);
        e[2] = fast_exp2(s[ti][2]);
        e[3] = fast_exp2(s[ti][3]);
        l4 += e;
        bf16x4 tb;
        tb[0] = (__bf16)e[0]; tb[1] = (__bf16)e[1];
        tb[2] = (__bf16)e[2]; tb[3] = (__bf16)e[3];
        pb[ti] = tb;
      }

      // O^T += V^T P^T (paired S^T tiles as B-frag)
#pragma unroll
      for (int t2 = 0; t2 < 2; ++t2) {
        union { bf16x4 hh[2]; bf16x8 v; } bp;
        bp.hh[0] = pb[2 * t2];
        bp.hh[1] = pb[2 * t2 + 1];
#pragma unroll
        for (int td = 0; td < 4; ++td) {
          int row = td * 16 + l16;
          int o1 = jh * 64 + t2 * 32 + quad * 4;
          int c1 = o1 >> 3, w1 = o1 & 7;
          int c2 = c1 + 2;
          union { uint2 u[2]; bf16x8 v; } tmp;
          tmp.u[0] = *(const uint2*)&sVt[row * 128 + ((c1 ^ (row & 15)) << 3) + w1];
          tmp.u[1] = *(const uint2*)&sVt[row * 128 + ((c2 ^ (row & 15)) << 3) + w1];
          oacc[td] = __builtin_amdgcn_mfma_f32_16x16x32_bf16(tmp.v, bp.v, oacc[td], 0, 0, 0);
        }
      }
    }
  }

  // epilogue (writes exactly the q rows this block read -> alias safe)
  float l = (l4[0] + l4[1]) + (l4[2] + l4[3]);
  l += __shfl_xor(l, 16);
  l += __shfl_xor(l, 32);
  float inv = 1.0f / l;
  int i_tok = m0 + w * 16 + l16;
#pragma unroll
  for (int td = 0; td < 4; ++td) {
    short tmp[4];
#pragma unroll
    for (int r = 0; r < 4; ++r) tmp[r] = bfbits(oacc[td][r] * inv);
    *(uint2*)(vect + base + (size_t)i_tok * 768 + td * 16 + quad * 4) = *(const uint2*)tmp;
  }
}

// --------------------------------------------------------------------------
// Out projection: 64x128 tile (grid 128x6 = 768 blocks), pure glds, bf16 ops.
// --------------------------------------------------------------------------
__global__ __launch_bounds__(256) void gemm_out(
    const short* __restrict__ vect, const short* __restrict__ wob,
    float* __restrict__ out) {
  const int m0 = blockIdx.x * 64;
  const int n0 = blockIdx.y * 128;
  const int tid = threadIdx.x;
  const int w = tid >> 6, lane = tid & 63, l16 = lane & 15, quad = lane >> 4;
  const int wr = w >> 1, wc = w & 1;

  __shared__ short sA[64 * 64];
  __shared__ short sB[128 * 64];

  f32x4 acc[2][4];
#pragma unroll
  for (int i = 0; i < 2; ++i)
#pragma unroll
    for (int j = 0; j < 4; ++j) acc[i][j] = (f32x4){0.f, 0.f, 0.f, 0.f};

  for (int k0 = 0; k0 < 768; k0 += 64) {
    __syncthreads();
    const short* Ab = vect + (size_t)m0 * 768 + k0;
    const short* Bb = wob + (size_t)n0 * 768 + k0;
#pragma unroll
    for (int p = 0; p < 2; ++p) {
      int lin = (w * 2 + p) * 64 + lane;
      int row = lin >> 3;
      int cs = ((lin & 7) ^ (row & 7)) * 8;
      glds16(Ab + (size_t)row * 768 + cs, &sA[lin * 8]);
    }
#pragma unroll
    for (int p = 0; p < 4; ++p) {
      int lin = (w * 4 + p) * 64 + lane;
      int row = lin >> 3;
      int cs = ((lin & 7) ^ (row & 7)) * 8;
      glds16(Bb + (size_t)row * 768 + cs, &sB[lin * 8]);
    }
    __syncthreads();
#pragma unroll
    for (int kk2 = 0; kk2 < 2; ++kk2) {
      bf16x8 af[2], bfg[4];
#pragma unroll
      for (int t = 0; t < 2; ++t) {
        int ra = wr * 32 + t * 16 + l16;
        af[t] = *(const bf16x8*)&sA[ra * 64 + (((kk2 * 4 + quad) ^ (ra & 7)) << 3)];
      }
#pragma unroll
      for (int t = 0; t < 4; ++t) {
        int rb = wc * 64 + t * 16 + l16;
        bfg[t] = *(const bf16x8*)&sB[rb * 64 + (((kk2 * 4 + quad) ^ (rb & 7)) << 3)];
      }
#pragma unroll
      for (int ti = 0; ti < 2; ++ti)
#pragma unroll
        for (int tj = 0; tj < 4; ++tj)
          acc[ti][tj] = __builtin_amdgcn_mfma_f32_16x16x32_bf16(af[ti], bfg[tj], acc[ti][tj], 0, 0, 0);
    }
  }
#pragma unroll
  for (int ti = 0; ti < 2; ++ti)
#pragma unroll
    for (int tj = 0; tj < 4; ++tj)
#pragma unroll
      for (int r = 0; r < 4; ++r) {
        int row = m0 + wr * 32 + ti * 16 + quad * 4 + r;
        int col = n0 + wc * 64 + tj * 16 + l16;
        out[(size_t)row * 768 + col] = acc[ti][tj][r];
      }
}

// --------------------------------------------------------------------------
extern "C" void kernel_launch(void* const* d_in, const int* in_sizes, int n_in,
                              void* d_out, int out_size, void* d_ws, size_t ws_size,
                              hipStream_t stream) {
  const float* x  = (const float*)d_in[0];
  const float* Wq = (const float*)d_in[1];
  const float* Wk = (const float*)d_in[2];
  const float* Wv = (const float*)d_in[3];
  const float* Wo = (const float*)d_in[4];
  float* out = (float*)d_out;

  const size_t MN = (size_t)8192 * 768;
  short* q    = (short*)d_ws;      // attn output (vect) aliases q
  short* k    = q + MN;
  short* vt   = k + MN;            // per-head transposed V: [96][64][1024]
  short* vect = q;                 // alias (attn writes exactly its own q rows)
  short* wob  = vt + MN;           // bf16 Wo, survives through gemm_out

  short* xb   = (short*)d_out;     // scratch in d_out head (dead before gemm_out)
  short* wqkv = xb + MN;

  convert_kernel<<<1056, 256, 0, stream>>>(x, Wq, Wk, Wv, Wo, xb, wqkv, wob);
  gemm_qkv<<<288, 512, 0, stream>>>(xb, wqkv, q, k, vt);
  attn_kernel<<<1536, 256, 0, stream>>>(q, k, vt, vect);
  gemm_out<<<dim3(128, 6), 256, 0, stream>>>(vect, wob, out);
}

// Round 2
// 194.066 us; speedup vs baseline: 1.0328x; 1.0328x over previous
//
#include <hip/hip_runtime.h>
#include <hip/hip_bf16.h>
#include <stdint.h>

// MetaAttention: x[8,1024,768] f32, Wq/Wk/Wv/Wo[768,768] f32 -> out[8,1024,768] f32
// Pipeline (4 kernels):
//   convert: x->xb, [Wq;Wk;Wv]->wqkv (d_out head scratch), Wo->wob (d_ws tail).
//   gemm_qkv: fused NT GEMM M=8192 N=2304 K=768. 128x256 tile, BK=64, 512 thr
//             (8 waves 2Mx4N, per-wave 64x64), depth-3 pipelined: 3 LDS buffers
//             (144 KiB), tile t+2 staged (glds16) during tile t, counted
//             vmcnt(6) per tile boundary, sched_barrier(0)-pinned MFMA phases,
//             T5 setprio, T2 XOR swizzle, T1 XCD swizzle (576 blocks, 576%8=0).
//             q pre-scaled by 0.125*log2(e); v stored per-head transposed vt.
//   attn: (b,h) x 64 q-rows per block (grid 1536, XCD remap); BJ=128 K/V tiles.
//   gemm_out: out = vect Wo^T, 64x128 tile (768 blocks), pure glds.
// d_ws (bf16): q/vect | k | vt | wob.

typedef __bf16 bf16x8 __attribute__((ext_vector_type(8)));
typedef __bf16 bf16x4 __attribute__((ext_vector_type(4)));
typedef float f32x4 __attribute__((ext_vector_type(4)));

#define GAS __attribute__((address_space(1)))
#define LAS __attribute__((address_space(3)))

__device__ __forceinline__ void glds16(const short* gp, short* lp) {
  __builtin_amdgcn_global_load_lds((const GAS void*)gp, (LAS void*)lp, 16, 0, 0);
}

__device__ __forceinline__ float fast_exp2(float x) {
#if __has_builtin(__builtin_amdgcn_exp2f)
  return __builtin_amdgcn_exp2f(x);
#else
  return __expf(x * 0.6931471805599453f);
#endif
}

__device__ __forceinline__ short bfbits(float f) {
  __bf16 b = (__bf16)f;                  // fptrunc RNE -> HW cvt
  union { __bf16 b; short s; } cv; cv.b = b;
  return cv.s;
}

__device__ __forceinline__ void stage8_f32(const float* __restrict__ src, short* dst) {
  float4 f0 = ((const float4*)src)[0];
  float4 f1 = ((const float4*)src)[1];
  bf16x8 t;
  t[0] = (__bf16)f0.x; t[1] = (__bf16)f0.y; t[2] = (__bf16)f0.z; t[3] = (__bf16)f0.w;
  t[4] = (__bf16)f1.x; t[5] = (__bf16)f1.y; t[6] = (__bf16)f1.z; t[7] = (__bf16)f1.w;
  *(bf16x8*)dst = t;
}

// --------------------------------------------------------------------------
// fp32 -> bf16 bulk conversion, flat exact grid: 1056 blocks x 1024 units.
// --------------------------------------------------------------------------
__global__ __launch_bounds__(256) void convert_kernel(
    const float* __restrict__ x, const float* __restrict__ Wq,
    const float* __restrict__ Wk, const float* __restrict__ Wv,
    const float* __restrict__ Wo,
    short* __restrict__ xb, short* __restrict__ wqkv, short* __restrict__ wob) {
  int u0 = blockIdx.x * 1024 + threadIdx.x;
#pragma unroll
  for (int i = 0; i < 4; ++i) {
    int u = u0 + i * 256;
    const float* src; short* dst;
    if (u < 786432) { src = x + (size_t)u * 8; dst = xb + (size_t)u * 8; }
    else if (u < 1007616) {
      int r = u - 786432;
      int wsel = r / 73728, off = r % 73728;
      const float* W = (wsel == 0) ? Wq : (wsel == 1) ? Wk : Wv;
      src = W + (size_t)off * 8;
      dst = wqkv + (size_t)r * 8;
    } else {
      int r = u - 1007616;
      src = Wo + (size_t)r * 8; dst = wob + (size_t)r * 8;
    }
    stage8_f32(src, dst);
  }
}

// --------------------------------------------------------------------------
// gemm_qkv helpers
// --------------------------------------------------------------------------
// Stage one 128x64 bf16 half-tile (16 KB): 1024 16B chunks, 2/thread @512thr.
// LDS dest linear in lane order (glds requirement); global source column
// pre-swizzled (chunk j of row r fetched from column (j ^ (r&7))*8) so the
// swizzled ds_read below sees conflict-free layout.
__device__ __forceinline__ void stage_half(const short* __restrict__ g, short* l,
                                           int w, int lane) {
#pragma unroll
  for (int p = 0; p < 2; ++p) {
    int c = (w * 2 + p) * 64 + lane;
    int row = c >> 3;
    int cs = ((c & 7) ^ (row & 7)) * 8;
    glds16(g + (size_t)row * 768 + cs, l + c * 8);
  }
}

__device__ __forceinline__ void bar_fence() {
  asm volatile("" ::: "memory");
  __builtin_amdgcn_s_barrier();
  asm volatile("" ::: "memory");
}

__device__ __forceinline__ void load_a8(const short* base, int wr, int l16, int quad,
                                        bf16x8 (&fa)[4][2]) {
#pragma unroll
  for (int mf = 0; mf < 4; ++mf)
#pragma unroll
    for (int kk = 0; kk < 2; ++kk) {
      int row = wr * 64 + mf * 16 + l16;
      fa[mf][kk] = *(const bf16x8*)&base[row * 64 + ((((kk << 2) + quad) ^ (row & 7)) << 3)];
    }
}

__device__ __forceinline__ void load_b4(const short* base, int rbase, int l16, int quad,
                                        bf16x8 (&fb)[2][2]) {
#pragma unroll
  for (int nf = 0; nf < 2; ++nf)
#pragma unroll
    for (int kk = 0; kk < 2; ++kk) {
      int row = rbase + nf * 16 + l16;
      fb[nf][kk] = *(const bf16x8*)&base[row * 64 + ((((kk << 2) + quad) ^ (row & 7)) << 3)];
    }
}

__device__ __forceinline__ void mma16(const bf16x8 (&fa)[4][2], const bf16x8 (&fb)[2][2],
                                      f32x4 (&acc)[4][4], int nf0) {
  __builtin_amdgcn_s_setprio(1);
#pragma unroll
  for (int kk = 0; kk < 2; ++kk)
#pragma unroll
    for (int mf = 0; mf < 4; ++mf)
#pragma unroll
      for (int nf = 0; nf < 2; ++nf)
        acc[mf][nf0 + nf] = __builtin_amdgcn_mfma_f32_16x16x32_bf16(
            fa[mf][kk], fb[nf][kk], acc[mf][nf0 + nf], 0, 0, 0);
  __builtin_amdgcn_s_setprio(0);
}

// --------------------------------------------------------------------------
// Fused QKV NT GEMM, 128x256 tile, BK=64, depth-3 pipeline, 2 phases/K-tile.
//
// Geometry: 8 waves 2Mx4N, per-wave output 64x64 (acc[4][4] = 64 VGPR).
// LDS: 3 buffers x (A 128x64 + B 256x64) bf16 = 3 x 48 KiB = 144 KiB.
//
// Per K-tile t (buf = t%3), 2 phases x {loads+stage | bar | MFMA(16) | bar}:
//   phA: rd fa(8), fb01(4); stage A(t+2), B.half0(t+2)
//   phB: rd fb23(4);        stage B.half1(t+2); vmcnt(6) -> tile t+1 landed
// In-flight: 6 loads/thread = 1 full tile staged 2 tiles ahead (~2 tile-times
// of HBM/L2 latency cover). vmcnt never drains to 0 except t=10 (prefetches
// skipped). sched_barrier(0) pins the MFMA cluster between its barriers
// (rule #18: memory clobbers alone don't order register-only MFMAs).
// --------------------------------------------------------------------------
__global__ __launch_bounds__(512, 2) void gemm_qkv(
    const short* __restrict__ xb, const short* __restrict__ wqkv,
    short* __restrict__ q, short* __restrict__ k, short* __restrict__ vt) {
  const int lin = blockIdx.x;
  const int swz = (lin & 7) * 72 + (lin >> 3);   // 576 % 8 == 0 -> bijective XCD swizzle
  const int bx = swz & 63;                       // M tile (64)
  const int by = swz >> 6;                       // N tile (9); XCD-neighbors share B panel
  const int m0 = bx * 128;
  const int n0g = by * 256;
  const int tid = threadIdx.x;
  const int w = tid >> 6, lane = tid & 63, l16 = lane & 15, quad = lane >> 4;
  const int wr = w >> 2, wc = w & 3;

  __shared__ short lds[3][24576];  // [buf][A:0..8191 | B:8192..24575]

  const short* Asrc = xb + (size_t)m0 * 768;
  const short* Bsrc = wqkv + (size_t)n0g * 768;

  f32x4 acc[4][4];
#pragma unroll
  for (int i = 0; i < 4; ++i)
#pragma unroll
    for (int j = 0; j < 4; ++j) acc[i][j] = (f32x4){0.f, 0.f, 0.f, 0.f};

  // prologue: stage tiles 0 and 1 fully (6 loads each); vmcnt(6) -> tile0 landed.
  stage_half(Asrc, &lds[0][0], w, lane);
  stage_half(Bsrc, &lds[0][8192], w, lane);
  stage_half(Bsrc + 98304, &lds[0][16384], w, lane);
  stage_half(Asrc + 64, &lds[1][0], w, lane);
  stage_half(Bsrc + 64, &lds[1][8192], w, lane);
  stage_half(Bsrc + 98304 + 64, &lds[1][16384], w, lane);
  asm volatile("s_waitcnt vmcnt(6)" ::: "memory");
  bar_fence();

  const int bh = wc >> 1;          // which 128-row half of B holds this wave's band
  const int rb0 = (wc & 1) * 64;   // row base within that half

  bf16x8 fa[4][2], fb0[2][2], fb1[2][2];

#pragma unroll
  for (int t = 0; t < 12; ++t) {
    const int buf = t % 3, nb = (t + 2) % 3;
    const bool pf = (t < 10);
    const short* A = &lds[buf][0];
    const short* Bb = &lds[buf][8192 + bh * 8192];

    // phase A
    load_a8(A, wr, l16, quad, fa);
    load_b4(Bb, rb0, l16, quad, fb0);
    if (pf) {
      stage_half(Asrc + (size_t)(t + 2) * 64, &lds[nb][0], w, lane);
      stage_half(Bsrc + (size_t)(t + 2) * 64, &lds[nb][8192], w, lane);
    }
    bar_fence();
    __builtin_amdgcn_sched_barrier(0);
    mma16(fa, fb0, acc, 0);
    __builtin_amdgcn_sched_barrier(0);
    bar_fence();

    // phase B
    load_b4(Bb, rb0 + 32, l16, quad, fb1);
    if (pf) {
      stage_half(Bsrc + 98304 + (size_t)(t + 2) * 64, &lds[nb][16384], w, lane);
      asm volatile("s_waitcnt vmcnt(6)" ::: "memory");   // tile t+1 fully landed
    } else if (t == 10) {
      asm volatile("s_waitcnt vmcnt(0)" ::: "memory");   // tail: tile 11 landed
    }
    bar_fence();
    __builtin_amdgcn_sched_barrier(0);
    mma16(fa, fb1, acc, 2);
    __builtin_amdgcn_sched_barrier(0);
    bar_fence();
  }

  // epilogue: same index convention as verified round-0/1 kernels:
  // rows m0 + wr*64 + mf*16 + quad*4 + r; cols nl0 + nf*16 + l16,
  // nl0 = (by%3)*256 + wc*64; wsel = by/3.
  const int wsel = by / 3;                    // 0:q 1:k 2:v
  const int nl0 = (by % 3) * 256 + wc * 64;
  if (wsel == 2) {
#pragma unroll
    for (int mf = 0; mf < 4; ++mf)
#pragma unroll
      for (int nf = 0; nf < 4; ++nf) {
        int token = m0 + wr * 64 + mf * 16 + quad * 4;  // +r contiguous
        int nl = nl0 + nf * 16 + l16;
        int bhh = (token >> 10) * 12 + (nl >> 6);
        short tmp[4];
#pragma unroll
        for (int r = 0; r < 4; ++r) tmp[r] = bfbits(acc[mf][nf][r]);
        *(uint2*)(vt + (size_t)bhh * 65536 + (size_t)(nl & 63) * 1024 + (token & 1023)) =
            *(const uint2*)tmp;
      }
  } else {
    short* C = wsel ? k : q;
    const float sc = wsel ? 1.0f : 0.1803368801111244f;  // q: 0.125*log2(e)
#pragma unroll
    for (int mf = 0; mf < 4; ++mf)
#pragma unroll
      for (int nf = 0; nf < 4; ++nf)
#pragma unroll
        for (int r = 0; r < 4; ++r) {
          int row = m0 + wr * 64 + mf * 16 + quad * 4 + r;
          int nl = nl0 + nf * 16 + l16;
          C[(size_t)row * 768 + nl] = bfbits(acc[mf][nf][r] * sc);
        }
  }
}

// --------------------------------------------------------------------------
// Flash attention: block = (b,h) x 64 q-rows, grid 1536 (XCD remap: idx%96=bh).
// BJ=128: per barrier-pair stage K[128x64] + V^T[64x128]; two 64-col compute
// halves reuse s[] regs. Q staged into sK space (frags->regs). LDS 32KB.
// S' = K Q'^T; P = exp2(S') in regs; paired-tile PV. vect aliases q.
// --------------------------------------------------------------------------
__global__ __launch_bounds__(256) void attn_kernel(
    const short* __restrict__ q, const short* __restrict__ k,
    const short* __restrict__ vt, short* __restrict__ vect) {
  const int bh = blockIdx.x % 96;
  const int qt = blockIdx.x / 96;
  const int b = bh / 12, h = bh % 12;
  const int m0 = qt * 64;
  const int tid = threadIdx.x;
  const int w = tid >> 6, lane = tid & 63, l16 = lane & 15, quad = lane >> 4;

  __shared__ short sK[128 * 64];   // K tile; also hosts Q during prologue
  __shared__ short sVt[64 * 128];  // V^T tile [d][j], 16 chunks/row

  const size_t base = (size_t)b * 786432 + (size_t)h * 64;
  const size_t vbase = (size_t)bh * 65536;

  // prologue: stage Q (64x64) into sK head, hoist fragments to registers
#pragma unroll
  for (int p = 0; p < 2; ++p) {
    int lin = (w * 2 + p) * 64 + lane;
    int row = lin >> 3;
    int cs = ((lin & 7) ^ (row & 7)) * 8;
    glds16(q + base + (size_t)(m0 + row) * 768 + cs, &sK[lin * 8]);
  }
  __syncthreads();
  bf16x8 bq[2];
#pragma unroll
  for (int kk = 0; kk < 2; ++kk) {
    int row = w * 16 + l16;
    bq[kk] = *(const bf16x8*)&sK[row * 64 + (((kk * 4 + quad) ^ (row & 7)) << 3)];
  }

  f32x4 l4 = (f32x4){0.f, 0.f, 0.f, 0.f};
  f32x4 oacc[4];
#pragma unroll
  for (int td = 0; td < 4; ++td) oacc[td] = (f32x4){0.f, 0.f, 0.f, 0.f};

  for (int j0 = 0; j0 < 1024; j0 += 128) {
    __syncthreads();  // prior reads retired (incl. bq prologue reads on iter 0)
    // stage K: 128 rows x 64 cols, 1024 chunks (4/thread), 8-chunk rows
#pragma unroll
    for (int p = 0; p < 4; ++p) {
      int lin = (w * 4 + p) * 64 + lane;
      int row = lin >> 3;
      int cs = ((lin & 7) ^ (row & 7)) * 8;
      glds16(k + base + (size_t)(j0 + row) * 768 + cs, &sK[lin * 8]);
    }
    // stage V^T: 64 rows x 128 cols, 1024 chunks (4/thread), 16-chunk rows
#pragma unroll
    for (int p = 0; p < 4; ++p) {
      int lin = (w * 4 + p) * 64 + lane;
      int row = lin >> 4;
      int c = lin & 15;
      int cs = (c ^ (row & 15)) * 8;
      glds16(vt + vbase + (size_t)row * 1024 + j0 + cs, &sVt[lin * 8]);
    }
    __syncthreads();

#pragma unroll
    for (int jh = 0; jh < 2; ++jh) {
      // S' tiles: rows j = jh*64 + ti*16 + quad*4+r, col i=l16
      f32x4 s[4];
#pragma unroll
      for (int ti = 0; ti < 4; ++ti) s[ti] = (f32x4){0.f, 0.f, 0.f, 0.f};
#pragma unroll
      for (int kk = 0; kk < 2; ++kk)
#pragma unroll
        for (int ti = 0; ti < 4; ++ti) {
          int row = jh * 64 + ti * 16 + l16;
          bf16x8 a = *(const bf16x8*)&sK[row * 64 + (((kk * 4 + quad) ^ (row & 7)) << 3)];
          s[ti] = __builtin_amdgcn_mfma_f32_16x16x32_bf16(a, bq[kk], s[ti], 0, 0, 0);
        }

      // P = exp2(S'); packed row-sum; HW packed bf16 convert
      bf16x4 pb[4];
#pragma unroll
      for (int ti = 0; ti < 4; ++ti) {
        f32x4 e;
        e[0] = fast_exp2(s[ti][0]);
        e[1] = fast_exp2(s[ti][1]);
        e[2] = fast_exp2(s[ti][2]);
        e[3] = fast_exp2(s[ti][3]);
        l4 += e;
        bf16x4 tb;
        tb[0] = (__bf16)e[0]; tb[1] = (__bf16)e[1];
        tb[2] = (__bf16)e[2]; tb[3] = (__bf16)e[3];
        pb[ti] = tb;
      }

      // O^T += V^T P^T (paired S^T tiles as B-frag)
#pragma unroll
      for (int t2 = 0; t2 < 2; ++t2) {
        union { bf16x4 hh[2]; bf16x8 v; } bp;
        bp.hh[0] = pb[2 * t2];
        bp.hh[1] = pb[2 * t2 + 1];
#pragma unroll
        for (int td = 0; td < 4; ++td) {
          int row = td * 16 + l16;
          int o1 = jh * 64 + t2 * 32 + quad * 4;
          int c1 = o1 >> 3, w1 = o1 & 7;
          int c2 = c1 + 2;
          union { uint2 u[2]; bf16x8 v; } tmp;
          tmp.u[0] = *(const uint2*)&sVt[row * 128 + ((c1 ^ (row & 15)) << 3) + w1];
          tmp.u[1] = *(const uint2*)&sVt[row * 128 + ((c2 ^ (row & 15)) << 3) + w1];
          oacc[td] = __builtin_amdgcn_mfma_f32_16x16x32_bf16(tmp.v, bp.v, oacc[td], 0, 0, 0);
        }
      }
    }
  }

  // epilogue (writes exactly the q rows this block read -> alias safe)
  float l = (l4[0] + l4[1]) + (l4[2] + l4[3]);
  l += __shfl_xor(l, 16);
  l += __shfl_xor(l, 32);
  float inv = 1.0f / l;
  int i_tok = m0 + w * 16 + l16;
#pragma unroll
  for (int td = 0; td < 4; ++td) {
    short tmp[4];
#pragma unroll
    for (int r = 0; r < 4; ++r) tmp[r] = bfbits(oacc[td][r] * inv);
    *(uint2*)(vect + base + (size_t)i_tok * 768 + td * 16 + quad * 4) = *(const uint2*)tmp;
  }
}

// --------------------------------------------------------------------------
// Out projection: 64x128 tile (grid 128x6 = 768 blocks), pure glds, bf16 ops.
// --------------------------------------------------------------------------
__global__ __launch_bounds__(256) void gemm_out(
    const short* __restrict__ vect, const short* __restrict__ wob,
    float* __restrict__ out) {
  const int m0 = blockIdx.x * 64;
  const int n0 = blockIdx.y * 128;
  const int tid = threadIdx.x;
  const int w = tid >> 6, lane = tid & 63, l16 = lane & 15, quad = lane >> 4;
  const int wr = w >> 1, wc = w & 1;

  __shared__ short sA[64 * 64];
  __shared__ short sB[128 * 64];

  f32x4 acc[2][4];
#pragma unroll
  for (int i = 0; i < 2; ++i)
#pragma unroll
    for (int j = 0; j < 4; ++j) acc[i][j] = (f32x4){0.f, 0.f, 0.f, 0.f};

  for (int k0 = 0; k0 < 768; k0 += 64) {
    __syncthreads();
    const short* Ab = vect + (size_t)m0 * 768 + k0;
    const short* Bb = wob + (size_t)n0 * 768 + k0;
#pragma unroll
    for (int p = 0; p < 2; ++p) {
      int lin = (w * 2 + p) * 64 + lane;
      int row = lin >> 3;
      int cs = ((lin & 7) ^ (row & 7)) * 8;
      glds16(Ab + (size_t)row * 768 + cs, &sA[lin * 8]);
    }
#pragma unroll
    for (int p = 0; p < 4; ++p) {
      int lin = (w * 4 + p) * 64 + lane;
      int row = lin >> 3;
      int cs = ((lin & 7) ^ (row & 7)) * 8;
      glds16(Bb + (size_t)row * 768 + cs, &sB[lin * 8]);
    }
    __syncthreads();
#pragma unroll
    for (int kk2 = 0; kk2 < 2; ++kk2) {
      bf16x8 af[2], bfg[4];
#pragma unroll
      for (int t = 0; t < 2; ++t) {
        int ra = wr * 32 + t * 16 + l16;
        af[t] = *(const bf16x8*)&sA[ra * 64 + (((kk2 * 4 + quad) ^ (ra & 7)) << 3)];
      }
#pragma unroll
      for (int t = 0; t < 4; ++t) {
        int rb = wc * 64 + t * 16 + l16;
        bfg[t] = *(const bf16x8*)&sB[rb * 64 + (((kk2 * 4 + quad) ^ (rb & 7)) << 3)];
      }
#pragma unroll
      for (int ti = 0; ti < 2; ++ti)
#pragma unroll
        for (int tj = 0; tj < 4; ++tj)
          acc[ti][tj] = __builtin_amdgcn_mfma_f32_16x16x32_bf16(af[ti], bfg[tj], acc[ti][tj], 0, 0, 0);
    }
  }
#pragma unroll
  for (int ti = 0; ti < 2; ++ti)
#pragma unroll
    for (int tj = 0; tj < 4; ++tj)
#pragma unroll
      for (int r = 0; r < 4; ++r) {
        int row = m0 + wr * 32 + ti * 16 + quad * 4 + r;
        int col = n0 + wc * 64 + tj * 16 + l16;
        out[(size_t)row * 768 + col] = acc[ti][tj][r];
      }
}

// --------------------------------------------------------------------------
extern "C" void kernel_launch(void* const* d_in, const int* in_sizes, int n_in,
                              void* d_out, int out_size, void* d_ws, size_t ws_size,
                              hipStream_t stream) {
  const float* x  = (const float*)d_in[0];
  const float* Wq = (const float*)d_in[1];
  const float* Wk = (const float*)d_in[2];
  const float* Wv = (const float*)d_in[3];
  const float* Wo = (const float*)d_in[4];
  float* out = (float*)d_out;

  const size_t MN = (size_t)8192 * 768;
  short* q    = (short*)d_ws;      // attn output (vect) aliases q
  short* k    = q + MN;
  short* vt   = k + MN;            // per-head transposed V: [96][64][1024]
  short* vect = q;                 // alias (attn writes exactly its own q rows)
  short* wob  = vt + MN;           // bf16 Wo, survives through gemm_out

  short* xb   = (short*)d_out;     // scratch in d_out head (dead before gemm_out)
  short* wqkv = xb + MN;

  convert_kernel<<<1056, 256, 0, stream>>>(x, Wq, Wk, Wv, Wo, xb, wqkv, wob);
  gemm_qkv<<<576, 512, 0, stream>>>(xb, wqkv, q, k, vt);
  attn_kernel<<<1536, 256, 0, stream>>>(q, k, vt, vect);
  gemm_out<<<dim3(128, 6), 256, 0, stream>>>(vect, wob, out);
}

// Round 3
// 184.308 us; speedup vs baseline: 1.0875x; 1.0529x over previous
//
#include <hip/hip_runtime.h>
#include <hip/hip_bf16.h>
#include <stdint.h>

// MetaAttention: x[8,1024,768] f32, Wq/Wk/Wv/Wo[768,768] f32 -> out[8,1024,768] f32
// Pipeline (4 kernels):
//   convert: x->xb, [Wq;Wk;Wv]->wqkv (d_out head scratch), Wo->wob (d_ws tail).
//   gemm_qkv: fused NT GEMM M=8192 N=2304 K=768. 128x256 tile, BK=64, 512 thr
//             (8 waves 2Mx4N, per-wave 64x64), depth-3 pipelined (verified r2).
//   attn: (b,h) x 128 q-rows per block (grid 768 = 96bh x 6? no: x 8 qt; XCD
//         remap idx%96=bh, 96%8==0 -> all qt of a bh share an XCD for K/V L2
//         reuse). Per j-tile: K/V A-frags loaded ONCE feed TWO q-row groups
//         (bq[g]/pb[g] in regs) -> LDS bytes per q-row halved vs r2.
//         LDS 32KB, 3 blocks/CU, whole grid resident (no tail rounds).
//   gemm_out: out = vect Wo^T, 64x128 tile (768 blocks), pure glds.
// d_ws (bf16): q/vect | k | vt | wob.

typedef __bf16 bf16x8 __attribute__((ext_vector_type(8)));
typedef __bf16 bf16x4 __attribute__((ext_vector_type(4)));
typedef float f32x4 __attribute__((ext_vector_type(4)));

#define GAS __attribute__((address_space(1)))
#define LAS __attribute__((address_space(3)))

__device__ __forceinline__ void glds16(const short* gp, short* lp) {
  __builtin_amdgcn_global_load_lds((const GAS void*)gp, (LAS void*)lp, 16, 0, 0);
}

__device__ __forceinline__ float fast_exp2(float x) {
#if __has_builtin(__builtin_amdgcn_exp2f)
  return __builtin_amdgcn_exp2f(x);
#else
  return __expf(x * 0.6931471805599453f);
#endif
}

__device__ __forceinline__ short bfbits(float f) {
  __bf16 b = (__bf16)f;                  // fptrunc RNE -> HW cvt
  union { __bf16 b; short s; } cv; cv.b = b;
  return cv.s;
}

__device__ __forceinline__ void stage8_f32(const float* __restrict__ src, short* dst) {
  float4 f0 = ((const float4*)src)[0];
  float4 f1 = ((const float4*)src)[1];
  bf16x8 t;
  t[0] = (__bf16)f0.x; t[1] = (__bf16)f0.y; t[2] = (__bf16)f0.z; t[3] = (__bf16)f0.w;
  t[4] = (__bf16)f1.x; t[5] = (__bf16)f1.y; t[6] = (__bf16)f1.z; t[7] = (__bf16)f1.w;
  *(bf16x8*)dst = t;
}

// --------------------------------------------------------------------------
// fp32 -> bf16 bulk conversion, flat exact grid: 1056 blocks x 1024 units.
// --------------------------------------------------------------------------
__global__ __launch_bounds__(256) void convert_kernel(
    const float* __restrict__ x, const float* __restrict__ Wq,
    const float* __restrict__ Wk, const float* __restrict__ Wv,
    const float* __restrict__ Wo,
    short* __restrict__ xb, short* __restrict__ wqkv, short* __restrict__ wob) {
  int u0 = blockIdx.x * 1024 + threadIdx.x;
#pragma unroll
  for (int i = 0; i < 4; ++i) {
    int u = u0 + i * 256;
    const float* src; short* dst;
    if (u < 786432) { src = x + (size_t)u * 8; dst = xb + (size_t)u * 8; }
    else if (u < 1007616) {
      int r = u - 786432;
      int wsel = r / 73728, off = r % 73728;
      const float* W = (wsel == 0) ? Wq : (wsel == 1) ? Wk : Wv;
      src = W + (size_t)off * 8;
      dst = wqkv + (size_t)r * 8;
    } else {
      int r = u - 1007616;
      src = Wo + (size_t)r * 8; dst = wob + (size_t)r * 8;
    }
    stage8_f32(src, dst);
  }
}

// --------------------------------------------------------------------------
// gemm_qkv helpers
// --------------------------------------------------------------------------
__device__ __forceinline__ void stage_half(const short* __restrict__ g, short* l,
                                           int w, int lane) {
#pragma unroll
  for (int p = 0; p < 2; ++p) {
    int c = (w * 2 + p) * 64 + lane;
    int row = c >> 3;
    int cs = ((c & 7) ^ (row & 7)) * 8;
    glds16(g + (size_t)row * 768 + cs, l + c * 8);
  }
}

__device__ __forceinline__ void bar_fence() {
  asm volatile("" ::: "memory");
  __builtin_amdgcn_s_barrier();
  asm volatile("" ::: "memory");
}

__device__ __forceinline__ void load_a8(const short* base, int wr, int l16, int quad,
                                        bf16x8 (&fa)[4][2]) {
#pragma unroll
  for (int mf = 0; mf < 4; ++mf)
#pragma unroll
    for (int kk = 0; kk < 2; ++kk) {
      int row = wr * 64 + mf * 16 + l16;
      fa[mf][kk] = *(const bf16x8*)&base[row * 64 + ((((kk << 2) + quad) ^ (row & 7)) << 3)];
    }
}

__device__ __forceinline__ void load_b4(const short* base, int rbase, int l16, int quad,
                                        bf16x8 (&fb)[2][2]) {
#pragma unroll
  for (int nf = 0; nf < 2; ++nf)
#pragma unroll
    for (int kk = 0; kk < 2; ++kk) {
      int row = rbase + nf * 16 + l16;
      fb[nf][kk] = *(const bf16x8*)&base[row * 64 + ((((kk << 2) + quad) ^ (row & 7)) << 3)];
    }
}

__device__ __forceinline__ void mma16(const bf16x8 (&fa)[4][2], const bf16x8 (&fb)[2][2],
                                      f32x4 (&acc)[4][4], int nf0) {
  __builtin_amdgcn_s_setprio(1);
#pragma unroll
  for (int kk = 0; kk < 2; ++kk)
#pragma unroll
    for (int mf = 0; mf < 4; ++mf)
#pragma unroll
      for (int nf = 0; nf < 2; ++nf)
        acc[mf][nf0 + nf] = __builtin_amdgcn_mfma_f32_16x16x32_bf16(
            fa[mf][kk], fb[nf][kk], acc[mf][nf0 + nf], 0, 0, 0);
  __builtin_amdgcn_s_setprio(0);
}

// --------------------------------------------------------------------------
// Fused QKV NT GEMM, 128x256 tile, BK=64, depth-3 pipeline, 2 phases/K-tile.
// (verified round-2 version, unchanged)
// --------------------------------------------------------------------------
__global__ __launch_bounds__(512, 2) void gemm_qkv(
    const short* __restrict__ xb, const short* __restrict__ wqkv,
    short* __restrict__ q, short* __restrict__ k, short* __restrict__ vt) {
  const int lin = blockIdx.x;
  const int swz = (lin & 7) * 72 + (lin >> 3);   // 576 % 8 == 0 -> bijective XCD swizzle
  const int bx = swz & 63;                       // M tile (64)
  const int by = swz >> 6;                       // N tile (9); XCD-neighbors share B panel
  const int m0 = bx * 128;
  const int n0g = by * 256;
  const int tid = threadIdx.x;
  const int w = tid >> 6, lane = tid & 63, l16 = lane & 15, quad = lane >> 4;
  const int wr = w >> 2, wc = w & 3;

  __shared__ short lds[3][24576];  // [buf][A:0..8191 | B:8192..24575]

  const short* Asrc = xb + (size_t)m0 * 768;
  const short* Bsrc = wqkv + (size_t)n0g * 768;

  f32x4 acc[4][4];
#pragma unroll
  for (int i = 0; i < 4; ++i)
#pragma unroll
    for (int j = 0; j < 4; ++j) acc[i][j] = (f32x4){0.f, 0.f, 0.f, 0.f};

  // prologue: stage tiles 0 and 1 fully (6 loads each); vmcnt(6) -> tile0 landed.
  stage_half(Asrc, &lds[0][0], w, lane);
  stage_half(Bsrc, &lds[0][8192], w, lane);
  stage_half(Bsrc + 98304, &lds[0][16384], w, lane);
  stage_half(Asrc + 64, &lds[1][0], w, lane);
  stage_half(Bsrc + 64, &lds[1][8192], w, lane);
  stage_half(Bsrc + 98304 + 64, &lds[1][16384], w, lane);
  asm volatile("s_waitcnt vmcnt(6)" ::: "memory");
  bar_fence();

  const int bh = wc >> 1;          // which 128-row half of B holds this wave's band
  const int rb0 = (wc & 1) * 64;   // row base within that half

  bf16x8 fa[4][2], fb0[2][2], fb1[2][2];

#pragma unroll
  for (int t = 0; t < 12; ++t) {
    const int buf = t % 3, nb = (t + 2) % 3;
    const bool pf = (t < 10);
    const short* A = &lds[buf][0];
    const short* Bb = &lds[buf][8192 + bh * 8192];

    // phase A
    load_a8(A, wr, l16, quad, fa);
    load_b4(Bb, rb0, l16, quad, fb0);
    if (pf) {
      stage_half(Asrc + (size_t)(t + 2) * 64, &lds[nb][0], w, lane);
      stage_half(Bsrc + (size_t)(t + 2) * 64, &lds[nb][8192], w, lane);
    }
    bar_fence();
    __builtin_amdgcn_sched_barrier(0);
    mma16(fa, fb0, acc, 0);
    __builtin_amdgcn_sched_barrier(0);
    bar_fence();

    // phase B
    load_b4(Bb, rb0 + 32, l16, quad, fb1);
    if (pf) {
      stage_half(Bsrc + 98304 + (size_t)(t + 2) * 64, &lds[nb][16384], w, lane);
      asm volatile("s_waitcnt vmcnt(6)" ::: "memory");   // tile t+1 fully landed
    } else if (t == 10) {
      asm volatile("s_waitcnt vmcnt(0)" ::: "memory");   // tail: tile 11 landed
    }
    bar_fence();
    __builtin_amdgcn_sched_barrier(0);
    mma16(fa, fb1, acc, 2);
    __builtin_amdgcn_sched_barrier(0);
    bar_fence();
  }

  // epilogue: rows m0 + wr*64 + mf*16 + quad*4 + r; cols nl0 + nf*16 + l16.
  const int wsel = by / 3;                    // 0:q 1:k 2:v
  const int nl0 = (by % 3) * 256 + wc * 64;
  if (wsel == 2) {
#pragma unroll
    for (int mf = 0; mf < 4; ++mf)
#pragma unroll
      for (int nf = 0; nf < 4; ++nf) {
        int token = m0 + wr * 64 + mf * 16 + quad * 4;  // +r contiguous
        int nl = nl0 + nf * 16 + l16;
        int bhh = (token >> 10) * 12 + (nl >> 6);
        short tmp[4];
#pragma unroll
        for (int r = 0; r < 4; ++r) tmp[r] = bfbits(acc[mf][nf][r]);
        *(uint2*)(vt + (size_t)bhh * 65536 + (size_t)(nl & 63) * 1024 + (token & 1023)) =
            *(const uint2*)tmp;
      }
  } else {
    short* C = wsel ? k : q;
    const float sc = wsel ? 1.0f : 0.1803368801111244f;  // q: 0.125*log2(e)
#pragma unroll
    for (int mf = 0; mf < 4; ++mf)
#pragma unroll
      for (int nf = 0; nf < 4; ++nf)
#pragma unroll
        for (int r = 0; r < 4; ++r) {
          int row = m0 + wr * 64 + mf * 16 + quad * 4 + r;
          int nl = nl0 + nf * 16 + l16;
          C[(size_t)row * 768 + nl] = bfbits(acc[mf][nf][r] * sc);
        }
  }
}

// --------------------------------------------------------------------------
// Flash attention: block = (b,h) x 128 q-rows, grid 768 (idx%96=bh -> all 8
// qt of a bh on one XCD, K/V L2-resident). 4 waves; each wave serves TWO
// 16-row q-groups (g=0: rows w*16+l16, g=1: +64). K/V A-fragments are read
// from LDS ONCE per j-tile and feed both groups' MFMAs (B-operands bq[g],
// pb[g] in regs) -> LDS bytes per q-row halved vs the 64-row version.
// BJ=128 K/V tiles; S' = K Q'^T; P = exp2(S') in regs; paired-tile PV.
// vect aliases q (block reads q only in its prologue, writes same rows last).
// --------------------------------------------------------------------------
__global__ __launch_bounds__(256, 3) void attn_kernel(
    const short* __restrict__ q, const short* __restrict__ k,
    const short* __restrict__ vt, short* __restrict__ vect) {
  const int bh = blockIdx.x % 96;
  const int qt = blockIdx.x / 96;          // 0..7
  const int b = bh / 12, h = bh % 12;
  const int m0 = qt * 128;
  const int tid = threadIdx.x;
  const int w = tid >> 6, lane = tid & 63, l16 = lane & 15, quad = lane >> 4;

  __shared__ short sK[128 * 64];   // K tile; hosts Q (128x64) during prologue
  __shared__ short sVt[64 * 128];  // V^T tile [d][j], 16 chunks/row

  const size_t base = (size_t)b * 786432 + (size_t)h * 64;
  const size_t vbase = (size_t)bh * 65536;

  // prologue: stage Q (128x64) into sK, hoist both groups' fragments to regs
#pragma unroll
  for (int p = 0; p < 4; ++p) {
    int lin = (w * 4 + p) * 64 + lane;
    int row = lin >> 3;
    int cs = ((lin & 7) ^ (row & 7)) * 8;
    glds16(q + base + (size_t)(m0 + row) * 768 + cs, &sK[lin * 8]);
  }
  __syncthreads();
  bf16x8 bq[2][2];
#pragma unroll
  for (int g = 0; g < 2; ++g)
#pragma unroll
    for (int kk = 0; kk < 2; ++kk) {
      int row = g * 64 + w * 16 + l16;
      bq[g][kk] = *(const bf16x8*)&sK[row * 64 + (((kk * 4 + quad) ^ (row & 7)) << 3)];
    }

  f32x4 l4[2];
  l4[0] = (f32x4){0.f, 0.f, 0.f, 0.f};
  l4[1] = (f32x4){0.f, 0.f, 0.f, 0.f};
  f32x4 oacc[2][4];
#pragma unroll
  for (int g = 0; g < 2; ++g)
#pragma unroll
    for (int td = 0; td < 4; ++td) oacc[g][td] = (f32x4){0.f, 0.f, 0.f, 0.f};

  for (int j0 = 0; j0 < 1024; j0 += 128) {
    __syncthreads();  // prior reads retired (incl. bq prologue reads on iter 0)
    // stage K: 128 rows x 64 cols, 1024 chunks (4/thread), 8-chunk rows
#pragma unroll
    for (int p = 0; p < 4; ++p) {
      int lin = (w * 4 + p) * 64 + lane;
      int row = lin >> 3;
      int cs = ((lin & 7) ^ (row & 7)) * 8;
      glds16(k + base + (size_t)(j0 + row) * 768 + cs, &sK[lin * 8]);
    }
    // stage V^T: 64 rows x 128 cols, 1024 chunks (4/thread), 16-chunk rows
#pragma unroll
    for (int p = 0; p < 4; ++p) {
      int lin = (w * 4 + p) * 64 + lane;
      int row = lin >> 4;
      int c = lin & 15;
      int cs = (c ^ (row & 15)) * 8;
      glds16(vt + vbase + (size_t)row * 1024 + j0 + cs, &sVt[lin * 8]);
    }
    __syncthreads();

#pragma unroll
    for (int jh = 0; jh < 2; ++jh) {
      // S' tiles for both groups: rows j = jh*64 + ti*16 + quad*4+r, col i=l16.
      // K A-frag loaded ONCE, used by both groups' MFMAs.
      f32x4 s[2][4];
#pragma unroll
      for (int g = 0; g < 2; ++g)
#pragma unroll
        for (int ti = 0; ti < 4; ++ti) s[g][ti] = (f32x4){0.f, 0.f, 0.f, 0.f};
#pragma unroll
      for (int kk = 0; kk < 2; ++kk)
#pragma unroll
        for (int ti = 0; ti < 4; ++ti) {
          int row = jh * 64 + ti * 16 + l16;
          bf16x8 a = *(const bf16x8*)&sK[row * 64 + (((kk * 4 + quad) ^ (row & 7)) << 3)];
          s[0][ti] = __builtin_amdgcn_mfma_f32_16x16x32_bf16(a, bq[0][kk], s[0][ti], 0, 0, 0);
          s[1][ti] = __builtin_amdgcn_mfma_f32_16x16x32_bf16(a, bq[1][kk], s[1][ti], 0, 0, 0);
        }

      // P = exp2(S'); packed row-sum; HW packed bf16 convert
      bf16x4 pb[2][4];
#pragma unroll
      for (int g = 0; g < 2; ++g)
#pragma unroll
        for (int ti = 0; ti < 4; ++ti) {
          f32x4 e;
          e[0] = fast_exp2(s[g][ti][0]);
          e[1] = fast_exp2(s[g][ti][1]);
          e[2] = fast_exp2(s[g][ti][2]);
          e[3] = fast_exp2(s[g][ti][3]);
          l4[g] += e;
          bf16x4 tb;
          tb[0] = (__bf16)e[0]; tb[1] = (__bf16)e[1];
          tb[2] = (__bf16)e[2]; tb[3] = (__bf16)e[3];
          pb[g][ti] = tb;
        }

      // O^T += V^T P^T (paired S^T tiles as B-frag); V A-frag loaded ONCE,
      // feeds both groups' MFMAs.
#pragma unroll
      for (int t2 = 0; t2 < 2; ++t2) {
        union { bf16x4 hh[2]; bf16x8 v; } bp0, bp1;
        bp0.hh[0] = pb[0][2 * t2];
        bp0.hh[1] = pb[0][2 * t2 + 1];
        bp1.hh[0] = pb[1][2 * t2];
        bp1.hh[1] = pb[1][2 * t2 + 1];
#pragma unroll
        for (int td = 0; td < 4; ++td) {
          int row = td * 16 + l16;
          int o1 = jh * 64 + t2 * 32 + quad * 4;
          int c1 = o1 >> 3, w1 = o1 & 7;
          int c2 = c1 + 2;
          union { uint2 u[2]; bf16x8 v; } tmp;
          tmp.u[0] = *(const uint2*)&sVt[row * 128 + ((c1 ^ (row & 15)) << 3) + w1];
          tmp.u[1] = *(const uint2*)&sVt[row * 128 + ((c2 ^ (row & 15)) << 3) + w1];
          oacc[0][td] = __builtin_amdgcn_mfma_f32_16x16x32_bf16(tmp.v, bp0.v, oacc[0][td], 0, 0, 0);
          oacc[1][td] = __builtin_amdgcn_mfma_f32_16x16x32_bf16(tmp.v, bp1.v, oacc[1][td], 0, 0, 0);
        }
      }
    }
  }

  // epilogue (writes exactly the q rows this block read -> alias safe)
#pragma unroll
  for (int g = 0; g < 2; ++g) {
    float l = (l4[g][0] + l4[g][1]) + (l4[g][2] + l4[g][3]);
    l += __shfl_xor(l, 16);
    l += __shfl_xor(l, 32);
    float inv = 1.0f / l;
    int i_tok = m0 + g * 64 + w * 16 + l16;
#pragma unroll
    for (int td = 0; td < 4; ++td) {
      short tmp[4];
#pragma unroll
      for (int r = 0; r < 4; ++r) tmp[r] = bfbits(oacc[g][td][r] * inv);
      *(uint2*)(vect + base + (size_t)i_tok * 768 + td * 16 + quad * 4) = *(const uint2*)tmp;
    }
  }
}

// --------------------------------------------------------------------------
// Out projection: 64x128 tile (grid 128x6 = 768 blocks), pure glds, bf16 ops.
// --------------------------------------------------------------------------
__global__ __launch_bounds__(256) void gemm_out(
    const short* __restrict__ vect, const short* __restrict__ wob,
    float* __restrict__ out) {
  const int m0 = blockIdx.x * 64;
  const int n0 = blockIdx.y * 128;
  const int tid = threadIdx.x;
  const int w = tid >> 6, lane = tid & 63, l16 = lane & 15, quad = lane >> 4;
  const int wr = w >> 1, wc = w & 1;

  __shared__ short sA[64 * 64];
  __shared__ short sB[128 * 64];

  f32x4 acc[2][4];
#pragma unroll
  for (int i = 0; i < 2; ++i)
#pragma unroll
    for (int j = 0; j < 4; ++j) acc[i][j] = (f32x4){0.f, 0.f, 0.f, 0.f};

  for (int k0 = 0; k0 < 768; k0 += 64) {
    __syncthreads();
    const short* Ab = vect + (size_t)m0 * 768 + k0;
    const short* Bb = wob + (size_t)n0 * 768 + k0;
#pragma unroll
    for (int p = 0; p < 2; ++p) {
      int lin = (w * 2 + p) * 64 + lane;
      int row = lin >> 3;
      int cs = ((lin & 7) ^ (row & 7)) * 8;
      glds16(Ab + (size_t)row * 768 + cs, &sA[lin * 8]);
    }
#pragma unroll
    for (int p = 0; p < 4; ++p) {
      int lin = (w * 4 + p) * 64 + lane;
      int row = lin >> 3;
      int cs = ((lin & 7) ^ (row & 7)) * 8;
      glds16(Bb + (size_t)row * 768 + cs, &sB[lin * 8]);
    }
    __syncthreads();
#pragma unroll
    for (int kk2 = 0; kk2 < 2; ++kk2) {
      bf16x8 af[2], bfg[4];
#pragma unroll
      for (int t = 0; t < 2; ++t) {
        int ra = wr * 32 + t * 16 + l16;
        af[t] = *(const bf16x8*)&sA[ra * 64 + (((kk2 * 4 + quad) ^ (ra & 7)) << 3)];
      }
#pragma unroll
      for (int t = 0; t < 4; ++t) {
        int rb = wc * 64 + t * 16 + l16;
        bfg[t] = *(const bf16x8*)&sB[rb * 64 + (((kk2 * 4 + quad) ^ (rb & 7)) << 3)];
      }
#pragma unroll
      for (int ti = 0; ti < 2; ++ti)
#pragma unroll
        for (int tj = 0; tj < 4; ++tj)
          acc[ti][tj] = __builtin_amdgcn_mfma_f32_16x16x32_bf16(af[ti], bfg[tj], acc[ti][tj], 0, 0, 0);
    }
  }
#pragma unroll
  for (int ti = 0; ti < 2; ++ti)
#pragma unroll
    for (int tj = 0; tj < 4; ++tj)
#pragma unroll
      for (int r = 0; r < 4; ++r) {
        int row = m0 + wr * 32 + ti * 16 + quad * 4 + r;
        int col = n0 + wc * 64 + tj * 16 + l16;
        out[(size_t)row * 768 + col] = acc[ti][tj][r];
      }
}

// --------------------------------------------------------------------------
extern "C" void kernel_launch(void* const* d_in, const int* in_sizes, int n_in,
                              void* d_out, int out_size, void* d_ws, size_t ws_size,
                              hipStream_t stream) {
  const float* x  = (const float*)d_in[0];
  const float* Wq = (const float*)d_in[1];
  const float* Wk = (const float*)d_in[2];
  const float* Wv = (const float*)d_in[3];
  const float* Wo = (const float*)d_in[4];
  float* out = (float*)d_out;

  const size_t MN = (size_t)8192 * 768;
  short* q    = (short*)d_ws;      // attn output (vect) aliases q
  short* k    = q + MN;
  short* vt   = k + MN;            // per-head transposed V: [96][64][1024]
  short* vect = q;                 // alias (attn writes exactly its own q rows)
  short* wob  = vt + MN;           // bf16 Wo, survives through gemm_out

  short* xb   = (short*)d_out;     // scratch in d_out head (dead before gemm_out)
  short* wqkv = xb + MN;

  convert_kernel<<<1056, 256, 0, stream>>>(x, Wq, Wk, Wv, Wo, xb, wqkv, wob);
  gemm_qkv<<<576, 512, 0, stream>>>(xb, wqkv, q, k, vt);
  attn_kernel<<<768, 256, 0, stream>>>(q, k, vt, vect);
  gemm_out<<<dim3(128, 6), 256, 0, stream>>>(vect, wob, out);
}

// Round 4
// 182.566 us; speedup vs baseline: 1.0979x; 1.0095x over previous
//
#include <hip/hip_runtime.h>
#include <hip/hip_bf16.h>
#include <stdint.h>

// MetaAttention: x[8,1024,768] f32, Wq/Wk/Wv/Wo[768,768] f32 -> out[8,1024,768] f32
// Pipeline (4 kernels):
//   convert: x->xb, [Wq;Wk;Wv]->wqkv (d_out head scratch), Wo->wob (d_ws tail).
//   gemm_qkv: fused NT GEMM M=8192 N=2304 K=768. 128x256 tile, BK=64, 512 thr
//             (8 waves 2Mx4N, per-wave 64x64), depth-3 pipelined (verified r2).
//             r4: XCD-LOCAL tiling — each XCD owns 8 consecutive bx x all 9 by
//             (72 blocks): A-panels (1.57MB) + concurrent B-panels stay L2-
//             resident per XCD; kills the cross-XCD A-panel refetch that made
//             staging stream at the HBM rate (FETCH 61MB vs 16MB unique).
//   attn: (b,h) x 128 q-rows per block (grid 768; idx%96=bh, 96%8==0 -> all qt
//         of a bh on one XCD). K/V A-frags read once feed two q-row groups.
//   gemm_out: out = vect Wo^T, 64x128 tile (768 blocks), pure glds.
// d_ws (bf16): q/vect | k | vt | wob.

typedef __bf16 bf16x8 __attribute__((ext_vector_type(8)));
typedef __bf16 bf16x4 __attribute__((ext_vector_type(4)));
typedef float f32x4 __attribute__((ext_vector_type(4)));

#define GAS __attribute__((address_space(1)))
#define LAS __attribute__((address_space(3)))

__device__ __forceinline__ void glds16(const short* gp, short* lp) {
  __builtin_amdgcn_global_load_lds((const GAS void*)gp, (LAS void*)lp, 16, 0, 0);
}

__device__ __forceinline__ float fast_exp2(float x) {
#if __has_builtin(__builtin_amdgcn_exp2f)
  return __builtin_amdgcn_exp2f(x);
#else
  return __expf(x * 0.6931471805599453f);
#endif
}

__device__ __forceinline__ short bfbits(float f) {
  __bf16 b = (__bf16)f;                  // fptrunc RNE -> HW cvt
  union { __bf16 b; short s; } cv; cv.b = b;
  return cv.s;
}

__device__ __forceinline__ void stage8_f32(const float* __restrict__ src, short* dst) {
  float4 f0 = ((const float4*)src)[0];
  float4 f1 = ((const float4*)src)[1];
  bf16x8 t;
  t[0] = (__bf16)f0.x; t[1] = (__bf16)f0.y; t[2] = (__bf16)f0.z; t[3] = (__bf16)f0.w;
  t[4] = (__bf16)f1.x; t[5] = (__bf16)f1.y; t[6] = (__bf16)f1.z; t[7] = (__bf16)f1.w;
  *(bf16x8*)dst = t;
}

// --------------------------------------------------------------------------
// fp32 -> bf16 bulk conversion, flat exact grid: 1056 blocks x 1024 units.
// --------------------------------------------------------------------------
__global__ __launch_bounds__(256) void convert_kernel(
    const float* __restrict__ x, const float* __restrict__ Wq,
    const float* __restrict__ Wk, const float* __restrict__ Wv,
    const float* __restrict__ Wo,
    short* __restrict__ xb, short* __restrict__ wqkv, short* __restrict__ wob) {
  int u0 = blockIdx.x * 1024 + threadIdx.x;
#pragma unroll
  for (int i = 0; i < 4; ++i) {
    int u = u0 + i * 256;
    const float* src; short* dst;
    if (u < 786432) { src = x + (size_t)u * 8; dst = xb + (size_t)u * 8; }
    else if (u < 1007616) {
      int r = u - 786432;
      int wsel = r / 73728, off = r % 73728;
      const float* W = (wsel == 0) ? Wq : (wsel == 1) ? Wk : Wv;
      src = W + (size_t)off * 8;
      dst = wqkv + (size_t)r * 8;
    } else {
      int r = u - 1007616;
      src = Wo + (size_t)r * 8; dst = wob + (size_t)r * 8;
    }
    stage8_f32(src, dst);
  }
}

// --------------------------------------------------------------------------
// gemm_qkv helpers
// --------------------------------------------------------------------------
__device__ __forceinline__ void stage_half(const short* __restrict__ g, short* l,
                                           int w, int lane) {
#pragma unroll
  for (int p = 0; p < 2; ++p) {
    int c = (w * 2 + p) * 64 + lane;
    int row = c >> 3;
    int cs = ((c & 7) ^ (row & 7)) * 8;
    glds16(g + (size_t)row * 768 + cs, l + c * 8);
  }
}

__device__ __forceinline__ void bar_fence() {
  asm volatile("" ::: "memory");
  __builtin_amdgcn_s_barrier();
  asm volatile("" ::: "memory");
}

__device__ __forceinline__ void load_a8(const short* base, int wr, int l16, int quad,
                                        bf16x8 (&fa)[4][2]) {
#pragma unroll
  for (int mf = 0; mf < 4; ++mf)
#pragma unroll
    for (int kk = 0; kk < 2; ++kk) {
      int row = wr * 64 + mf * 16 + l16;
      fa[mf][kk] = *(const bf16x8*)&base[row * 64 + ((((kk << 2) + quad) ^ (row & 7)) << 3)];
    }
}

__device__ __forceinline__ void load_b4(const short* base, int rbase, int l16, int quad,
                                        bf16x8 (&fb)[2][2]) {
#pragma unroll
  for (int nf = 0; nf < 2; ++nf)
#pragma unroll
    for (int kk = 0; kk < 2; ++kk) {
      int row = rbase + nf * 16 + l16;
      fb[nf][kk] = *(const bf16x8*)&base[row * 64 + ((((kk << 2) + quad) ^ (row & 7)) << 3)];
    }
}

__device__ __forceinline__ void mma16(const bf16x8 (&fa)[4][2], const bf16x8 (&fb)[2][2],
                                      f32x4 (&acc)[4][4], int nf0) {
  __builtin_amdgcn_s_setprio(1);
#pragma unroll
  for (int kk = 0; kk < 2; ++kk)
#pragma unroll
    for (int mf = 0; mf < 4; ++mf)
#pragma unroll
      for (int nf = 0; nf < 2; ++nf)
        acc[mf][nf0 + nf] = __builtin_amdgcn_mfma_f32_16x16x32_bf16(
            fa[mf][kk], fb[nf][kk], acc[mf][nf0 + nf], 0, 0, 0);
  __builtin_amdgcn_s_setprio(0);
}

// --------------------------------------------------------------------------
// Fused QKV NT GEMM, 128x256 tile, BK=64, depth-3 pipeline, 2 phases/K-tile.
// r4: XCD-local block mapping. xcd = lin&7 (dispatch round-robin), each XCD
// owns bx in [xcd*8, xcd*8+8) x by 0..8. Per-XCD L2 working set: 8 A-panels
// (1.57MB) + <=4 concurrent B-panels (1.57MB) < 4MB; rounds 2-3 re-hit warm
// A-panels. Staging now streams from local L2 (~60 B/cyc/CU) instead of
// HBM/L3 (~10 B/cyc/CU observed in r2/r3).
// --------------------------------------------------------------------------
__global__ __launch_bounds__(512, 2) void gemm_qkv(
    const short* __restrict__ xb, const short* __restrict__ wqkv,
    short* __restrict__ q, short* __restrict__ k, short* __restrict__ vt) {
  const int lin = blockIdx.x;
  const int xcd = lin & 7, grp = lin >> 3;       // 576 blocks: 72 per XCD
  const int by = grp >> 3;                       // 0..8 (N tile); grp&7 fastest ->
  const int bx = xcd * 8 + (grp & 7);            //   8 bx concurrent per by-round
  const int m0 = bx * 128;
  const int n0g = by * 256;
  const int tid = threadIdx.x;
  const int w = tid >> 6, lane = tid & 63, l16 = lane & 15, quad = lane >> 4;
  const int wr = w >> 2, wc = w & 3;

  __shared__ short lds[3][24576];  // [buf][A:0..8191 | B:8192..24575]

  const short* Asrc = xb + (size_t)m0 * 768;
  const short* Bsrc = wqkv + (size_t)n0g * 768;

  f32x4 acc[4][4];
#pragma unroll
  for (int i = 0; i < 4; ++i)
#pragma unroll
    for (int j = 0; j < 4; ++j) acc[i][j] = (f32x4){0.f, 0.f, 0.f, 0.f};

  // prologue: stage tiles 0 and 1 fully (6 loads each); vmcnt(6) -> tile0 landed.
  stage_half(Asrc, &lds[0][0], w, lane);
  stage_half(Bsrc, &lds[0][8192], w, lane);
  stage_half(Bsrc + 98304, &lds[0][16384], w, lane);
  stage_half(Asrc + 64, &lds[1][0], w, lane);
  stage_half(Bsrc + 64, &lds[1][8192], w, lane);
  stage_half(Bsrc + 98304 + 64, &lds[1][16384], w, lane);
  asm volatile("s_waitcnt vmcnt(6)" ::: "memory");
  bar_fence();

  const int bh = wc >> 1;          // which 128-row half of B holds this wave's band
  const int rb0 = (wc & 1) * 64;   // row base within that half

  bf16x8 fa[4][2], fb0[2][2], fb1[2][2];

#pragma unroll
  for (int t = 0; t < 12; ++t) {
    const int buf = t % 3, nb = (t + 2) % 3;
    const bool pf = (t < 10);
    const short* A = &lds[buf][0];
    const short* Bb = &lds[buf][8192 + bh * 8192];

    // phase A
    load_a8(A, wr, l16, quad, fa);
    load_b4(Bb, rb0, l16, quad, fb0);
    if (pf) {
      stage_half(Asrc + (size_t)(t + 2) * 64, &lds[nb][0], w, lane);
      stage_half(Bsrc + (size_t)(t + 2) * 64, &lds[nb][8192], w, lane);
    }
    bar_fence();
    __builtin_amdgcn_sched_barrier(0);
    mma16(fa, fb0, acc, 0);
    __builtin_amdgcn_sched_barrier(0);
    bar_fence();

    // phase B
    load_b4(Bb, rb0 + 32, l16, quad, fb1);
    if (pf) {
      stage_half(Bsrc + 98304 + (size_t)(t + 2) * 64, &lds[nb][16384], w, lane);
      asm volatile("s_waitcnt vmcnt(6)" ::: "memory");   // tile t+1 fully landed
    } else if (t == 10) {
      asm volatile("s_waitcnt vmcnt(0)" ::: "memory");   // tail: tile 11 landed
    }
    bar_fence();
    __builtin_amdgcn_sched_barrier(0);
    mma16(fa, fb1, acc, 2);
    __builtin_amdgcn_sched_barrier(0);
    bar_fence();
  }

  // epilogue: rows m0 + wr*64 + mf*16 + quad*4 + r; cols nl0 + nf*16 + l16.
  const int wsel = by / 3;                    // 0:q 1:k 2:v
  const int nl0 = (by % 3) * 256 + wc * 64;
  if (wsel == 2) {
#pragma unroll
    for (int mf = 0; mf < 4; ++mf)
#pragma unroll
      for (int nf = 0; nf < 4; ++nf) {
        int token = m0 + wr * 64 + mf * 16 + quad * 4;  // +r contiguous
        int nl = nl0 + nf * 16 + l16;
        int bhh = (token >> 10) * 12 + (nl >> 6);
        short tmp[4];
#pragma unroll
        for (int r = 0; r < 4; ++r) tmp[r] = bfbits(acc[mf][nf][r]);
        *(uint2*)(vt + (size_t)bhh * 65536 + (size_t)(nl & 63) * 1024 + (token & 1023)) =
            *(const uint2*)tmp;
      }
  } else {
    short* C = wsel ? k : q;
    const float sc = wsel ? 1.0f : 0.1803368801111244f;  // q: 0.125*log2(e)
#pragma unroll
    for (int mf = 0; mf < 4; ++mf)
#pragma unroll
      for (int nf = 0; nf < 4; ++nf)
#pragma unroll
        for (int r = 0; r < 4; ++r) {
          int row = m0 + wr * 64 + mf * 16 + quad * 4 + r;
          int nl = nl0 + nf * 16 + l16;
          C[(size_t)row * 768 + nl] = bfbits(acc[mf][nf][r] * sc);
        }
  }
}

// --------------------------------------------------------------------------
// Flash attention: block = (b,h) x 128 q-rows, grid 768 (idx%96=bh -> all 8
// qt of a bh on one XCD, K/V L2-resident). 4 waves; each wave serves TWO
// 16-row q-groups (g=0: rows w*16+l16, g=1: +64). K/V A-fragments are read
// from LDS ONCE per j-tile and feed both groups' MFMAs (B-operands bq[g],
// pb[g] in regs) -> LDS bytes per q-row halved vs the 64-row version.
// BJ=128 K/V tiles; S' = K Q'^T; P = exp2(S') in regs; paired-tile PV.
// vect aliases q (block reads q only in its prologue, writes same rows last).
// --------------------------------------------------------------------------
__global__ __launch_bounds__(256, 3) void attn_kernel(
    const short* __restrict__ q, const short* __restrict__ k,
    const short* __restrict__ vt, short* __restrict__ vect) {
  const int bh = blockIdx.x % 96;
  const int qt = blockIdx.x / 96;          // 0..7
  const int b = bh / 12, h = bh % 12;
  const int m0 = qt * 128;
  const int tid = threadIdx.x;
  const int w = tid >> 6, lane = tid & 63, l16 = lane & 15, quad = lane >> 4;

  __shared__ short sK[128 * 64];   // K tile; hosts Q (128x64) during prologue
  __shared__ short sVt[64 * 128];  // V^T tile [d][j], 16 chunks/row

  const size_t base = (size_t)b * 786432 + (size_t)h * 64;
  const size_t vbase = (size_t)bh * 65536;

  // prologue: stage Q (128x64) into sK, hoist both groups' fragments to regs
#pragma unroll
  for (int p = 0; p < 4; ++p) {
    int lin = (w * 4 + p) * 64 + lane;
    int row = lin >> 3;
    int cs = ((lin & 7) ^ (row & 7)) * 8;
    glds16(q + base + (size_t)(m0 + row) * 768 + cs, &sK[lin * 8]);
  }
  __syncthreads();
  bf16x8 bq[2][2];
#pragma unroll
  for (int g = 0; g < 2; ++g)
#pragma unroll
    for (int kk = 0; kk < 2; ++kk) {
      int row = g * 64 + w * 16 + l16;
      bq[g][kk] = *(const bf16x8*)&sK[row * 64 + (((kk * 4 + quad) ^ (row & 7)) << 3)];
    }

  f32x4 l4[2];
  l4[0] = (f32x4){0.f, 0.f, 0.f, 0.f};
  l4[1] = (f32x4){0.f, 0.f, 0.f, 0.f};
  f32x4 oacc[2][4];
#pragma unroll
  for (int g = 0; g < 2; ++g)
#pragma unroll
    for (int td = 0; td < 4; ++td) oacc[g][td] = (f32x4){0.f, 0.f, 0.f, 0.f};

  for (int j0 = 0; j0 < 1024; j0 += 128) {
    __syncthreads();  // prior reads retired (incl. bq prologue reads on iter 0)
    // stage K: 128 rows x 64 cols, 1024 chunks (4/thread), 8-chunk rows
#pragma unroll
    for (int p = 0; p < 4; ++p) {
      int lin = (w * 4 + p) * 64 + lane;
      int row = lin >> 3;
      int cs = ((lin & 7) ^ (row & 7)) * 8;
      glds16(k + base + (size_t)(j0 + row) * 768 + cs, &sK[lin * 8]);
    }
    // stage V^T: 64 rows x 128 cols, 1024 chunks (4/thread), 16-chunk rows
#pragma unroll
    for (int p = 0; p < 4; ++p) {
      int lin = (w * 4 + p) * 64 + lane;
      int row = lin >> 4;
      int c = lin & 15;
      int cs = (c ^ (row & 15)) * 8;
      glds16(vt + vbase + (size_t)row * 1024 + j0 + cs, &sVt[lin * 8]);
    }
    __syncthreads();

#pragma unroll
    for (int jh = 0; jh < 2; ++jh) {
      // S' tiles for both groups: rows j = jh*64 + ti*16 + quad*4+r, col i=l16.
      // K A-frag loaded ONCE, used by both groups' MFMAs.
      f32x4 s[2][4];
#pragma unroll
      for (int g = 0; g < 2; ++g)
#pragma unroll
        for (int ti = 0; ti < 4; ++ti) s[g][ti] = (f32x4){0.f, 0.f, 0.f, 0.f};
#pragma unroll
      for (int kk = 0; kk < 2; ++kk)
#pragma unroll
        for (int ti = 0; ti < 4; ++ti) {
          int row = jh * 64 + ti * 16 + l16;
          bf16x8 a = *(const bf16x8*)&sK[row * 64 + (((kk * 4 + quad) ^ (row & 7)) << 3)];
          s[0][ti] = __builtin_amdgcn_mfma_f32_16x16x32_bf16(a, bq[0][kk], s[0][ti], 0, 0, 0);
          s[1][ti] = __builtin_amdgcn_mfma_f32_16x16x32_bf16(a, bq[1][kk], s[1][ti], 0, 0, 0);
        }

      // P = exp2(S'); packed row-sum; HW packed bf16 convert
      bf16x4 pb[2][4];
#pragma unroll
      for (int g = 0; g < 2; ++g)
#pragma unroll
        for (int ti = 0; ti < 4; ++ti) {
          f32x4 e;
          e[0] = fast_exp2(s[g][ti][0]);
          e[1] = fast_exp2(s[g][ti][1]);
          e[2] = fast_exp2(s[g][ti][2]);
          e[3] = fast_exp2(s[g][ti][3]);
          l4[g] += e;
          bf16x4 tb;
          tb[0] = (__bf16)e[0]; tb[1] = (__bf16)e[1];
          tb[2] = (__bf16)e[2]; tb[3] = (__bf16)e[3];
          pb[g][ti] = tb;
        }

      // O^T += V^T P^T (paired S^T tiles as B-frag); V A-frag loaded ONCE,
      // feeds both groups' MFMAs.
#pragma unroll
      for (int t2 = 0; t2 < 2; ++t2) {
        union { bf16x4 hh[2]; bf16x8 v; } bp0, bp1;
        bp0.hh[0] = pb[0][2 * t2];
        bp0.hh[1] = pb[0][2 * t2 + 1];
        bp1.hh[0] = pb[1][2 * t2];
        bp1.hh[1] = pb[1][2 * t2 + 1];
#pragma unroll
        for (int td = 0; td < 4; ++td) {
          int row = td * 16 + l16;
          int o1 = jh * 64 + t2 * 32 + quad * 4;
          int c1 = o1 >> 3, w1 = o1 & 7;
          int c2 = c1 + 2;
          union { uint2 u[2]; bf16x8 v; } tmp;
          tmp.u[0] = *(const uint2*)&sVt[row * 128 + ((c1 ^ (row & 15)) << 3) + w1];
          tmp.u[1] = *(const uint2*)&sVt[row * 128 + ((c2 ^ (row & 15)) << 3) + w1];
          oacc[0][td] = __builtin_amdgcn_mfma_f32_16x16x32_bf16(tmp.v, bp0.v, oacc[0][td], 0, 0, 0);
          oacc[1][td] = __builtin_amdgcn_mfma_f32_16x16x32_bf16(tmp.v, bp1.v, oacc[1][td], 0, 0, 0);
        }
      }
    }
  }

  // epilogue (writes exactly the q rows this block read -> alias safe)
#pragma unroll
  for (int g = 0; g < 2; ++g) {
    float l = (l4[g][0] + l4[g][1]) + (l4[g][2] + l4[g][3]);
    l += __shfl_xor(l, 16);
    l += __shfl_xor(l, 32);
    float inv = 1.0f / l;
    int i_tok = m0 + g * 64 + w * 16 + l16;
#pragma unroll
    for (int td = 0; td < 4; ++td) {
      short tmp[4];
#pragma unroll
      for (int r = 0; r < 4; ++r) tmp[r] = bfbits(oacc[g][td][r] * inv);
      *(uint2*)(vect + base + (size_t)i_tok * 768 + td * 16 + quad * 4) = *(const uint2*)tmp;
    }
  }
}

// --------------------------------------------------------------------------
// Out projection: 64x128 tile (grid 128x6 = 768 blocks), pure glds, bf16 ops.
// --------------------------------------------------------------------------
__global__ __launch_bounds__(256) void gemm_out(
    const short* __restrict__ vect, const short* __restrict__ wob,
    float* __restrict__ out) {
  const int m0 = blockIdx.x * 64;
  const int n0 = blockIdx.y * 128;
  const int tid = threadIdx.x;
  const int w = tid >> 6, lane = tid & 63, l16 = lane & 15, quad = lane >> 4;
  const int wr = w >> 1, wc = w & 1;

  __shared__ short sA[64 * 64];
  __shared__ short sB[128 * 64];

  f32x4 acc[2][4];
#pragma unroll
  for (int i = 0; i < 2; ++i)
#pragma unroll
    for (int j = 0; j < 4; ++j) acc[i][j] = (f32x4){0.f, 0.f, 0.f, 0.f};

  for (int k0 = 0; k0 < 768; k0 += 64) {
    __syncthreads();
    const short* Ab = vect + (size_t)m0 * 768 + k0;
    const short* Bb = wob + (size_t)n0 * 768 + k0;
#pragma unroll
    for (int p = 0; p < 2; ++p) {
      int lin = (w * 2 + p) * 64 + lane;
      int row = lin >> 3;
      int cs = ((lin & 7) ^ (row & 7)) * 8;
      glds16(Ab + (size_t)row * 768 + cs, &sA[lin * 8]);
    }
#pragma unroll
    for (int p = 0; p < 4; ++p) {
      int lin = (w * 4 + p) * 64 + lane;
      int row = lin >> 3;
      int cs = ((lin & 7) ^ (row & 7)) * 8;
      glds16(Bb + (size_t)row * 768 + cs, &sB[lin * 8]);
    }
    __syncthreads();
#pragma unroll
    for (int kk2 = 0; kk2 < 2; ++kk2) {
      bf16x8 af[2], bfg[4];
#pragma unroll
      for (int t = 0; t < 2; ++t) {
        int ra = wr * 32 + t * 16 + l16;
        af[t] = *(const bf16x8*)&sA[ra * 64 + (((kk2 * 4 + quad) ^ (ra & 7)) << 3)];
      }
#pragma unroll
      for (int t = 0; t < 4; ++t) {
        int rb = wc * 64 + t * 16 + l16;
        bfg[t] = *(const bf16x8*)&sB[rb * 64 + (((kk2 * 4 + quad) ^ (rb & 7)) << 3)];
      }
#pragma unroll
      for (int ti = 0; ti < 2; ++ti)
#pragma unroll
        for (int tj = 0; tj < 4; ++tj)
          acc[ti][tj] = __builtin_amdgcn_mfma_f32_16x16x32_bf16(af[ti], bfg[tj], acc[ti][tj], 0, 0, 0);
    }
  }
#pragma unroll
  for (int ti = 0; ti < 2; ++ti)
#pragma unroll
    for (int tj = 0; tj < 4; ++tj)
#pragma unroll
      for (int r = 0; r < 4; ++r) {
        int row = m0 + wr * 32 + ti * 16 + quad * 4 + r;
        int col = n0 + wc * 64 + tj * 16 + l16;
        out[(size_t)row * 768 + col] = acc[ti][tj][r];
      }
}

// --------------------------------------------------------------------------
extern "C" void kernel_launch(void* const* d_in, const int* in_sizes, int n_in,
                              void* d_out, int out_size, void* d_ws, size_t ws_size,
                              hipStream_t stream) {
  const float* x  = (const float*)d_in[0];
  const float* Wq = (const float*)d_in[1];
  const float* Wk = (const float*)d_in[2];
  const float* Wv = (const float*)d_in[3];
  const float* Wo = (const float*)d_in[4];
  float* out = (float*)d_out;

  const size_t MN = (size_t)8192 * 768;
  short* q    = (short*)d_ws;      // attn output (vect) aliases q
  short* k    = q + MN;
  short* vt   = k + MN;            // per-head transposed V: [96][64][1024]
  short* vect = q;                 // alias (attn writes exactly its own q rows)
  short* wob  = vt + MN;           // bf16 Wo, survives through gemm_out

  short* xb   = (short*)d_out;     // scratch in d_out head (dead before gemm_out)
  short* wqkv = xb + MN;

  convert_kernel<<<1056, 256, 0, stream>>>(x, Wq, Wk, Wv, Wo, xb, wqkv, wob);
  gemm_qkv<<<576, 512, 0, stream>>>(xb, wqkv, q, k, vt);
  attn_kernel<<<768, 256, 0, stream>>>(q, k, vt, vect);
  gemm_out<<<dim3(128, 6), 256, 0, stream>>>(vect, wob, out);
}

// Round 5
// 176.109 us; speedup vs baseline: 1.1381x; 1.0367x over previous
//
#include <hip/hip_runtime.h>
#include <hip/hip_bf16.h>
#include <stdint.h>

// MetaAttention: x[8,1024,768] f32, Wq/Wk/Wv/Wo[768,768] f32 -> out[8,1024,768] f32
// Pipeline (4 kernels):
//   convert: x->xb, [Wq;Wk;Wv]->wqkv (d_out head scratch), Wo->wob (d_ws tail).
//   gemm_qkv: fused NT GEMM M=8192 N=2304 K=768. 128x256 tile, BK=64, 512 thr,
//             depth-3 pipelined, XCD-local tiling (verified r4, unchanged).
//   attn: (b,h) x 128 q-rows per block (grid 768; idx%96=bh). r5: K/V staging
//         pipelined under compute — K(j+1) issued after QK(j) (lands under
//         softmax+PV), V(j+1) issued after PV(j) (lands under next QK); raw
//         s_barrier + per-wave counted vmcnt(4), never drained mid-loop.
//         32KB LDS, 3 blocks/CU preserved.
//   gemm_out: r5: 128x192 tile, grid 256 (=1/CU exact fill), depth-3 counted
//             vmcnt pipeline, XCD-local (Wo+8 A-panels L2-resident/XCD).
// d_ws (bf16): q/vect | k | vt | wob.

typedef __bf16 bf16x8 __attribute__((ext_vector_type(8)));
typedef __bf16 bf16x4 __attribute__((ext_vector_type(4)));
typedef float f32x4 __attribute__((ext_vector_type(4)));

#define GAS __attribute__((address_space(1)))
#define LAS __attribute__((address_space(3)))

__device__ __forceinline__ void glds16(const short* gp, short* lp) {
  __builtin_amdgcn_global_load_lds((const GAS void*)gp, (LAS void*)lp, 16, 0, 0);
}

__device__ __forceinline__ float fast_exp2(float x) {
#if __has_builtin(__builtin_amdgcn_exp2f)
  return __builtin_amdgcn_exp2f(x);
#else
  return __expf(x * 0.6931471805599453f);
#endif
}

__device__ __forceinline__ short bfbits(float f) {
  __bf16 b = (__bf16)f;                  // fptrunc RNE -> HW cvt
  union { __bf16 b; short s; } cv; cv.b = b;
  return cv.s;
}

__device__ __forceinline__ void stage8_f32(const float* __restrict__ src, short* dst) {
  float4 f0 = ((const float4*)src)[0];
  float4 f1 = ((const float4*)src)[1];
  bf16x8 t;
  t[0] = (__bf16)f0.x; t[1] = (__bf16)f0.y; t[2] = (__bf16)f0.z; t[3] = (__bf16)f0.w;
  t[4] = (__bf16)f1.x; t[5] = (__bf16)f1.y; t[6] = (__bf16)f1.z; t[7] = (__bf16)f1.w;
  *(bf16x8*)dst = t;
}

// --------------------------------------------------------------------------
// fp32 -> bf16 bulk conversion, flat exact grid: 1056 blocks x 1024 units.
// --------------------------------------------------------------------------
__global__ __launch_bounds__(256) void convert_kernel(
    const float* __restrict__ x, const float* __restrict__ Wq,
    const float* __restrict__ Wk, const float* __restrict__ Wv,
    const float* __restrict__ Wo,
    short* __restrict__ xb, short* __restrict__ wqkv, short* __restrict__ wob) {
  int u0 = blockIdx.x * 1024 + threadIdx.x;
#pragma unroll
  for (int i = 0; i < 4; ++i) {
    int u = u0 + i * 256;
    const float* src; short* dst;
    if (u < 786432) { src = x + (size_t)u * 8; dst = xb + (size_t)u * 8; }
    else if (u < 1007616) {
      int r = u - 786432;
      int wsel = r / 73728, off = r % 73728;
      const float* W = (wsel == 0) ? Wq : (wsel == 1) ? Wk : Wv;
      src = W + (size_t)off * 8;
      dst = wqkv + (size_t)r * 8;
    } else {
      int r = u - 1007616;
      src = Wo + (size_t)r * 8; dst = wob + (size_t)r * 8;
    }
    stage8_f32(src, dst);
  }
}

// --------------------------------------------------------------------------
// shared GEMM helpers
// --------------------------------------------------------------------------
__device__ __forceinline__ void stage_half(const short* __restrict__ g, short* l,
                                           int w, int lane) {
#pragma unroll
  for (int p = 0; p < 2; ++p) {
    int c = (w * 2 + p) * 64 + lane;
    int row = c >> 3;
    int cs = ((c & 7) ^ (row & 7)) * 8;
    glds16(g + (size_t)row * 768 + cs, l + c * 8);
  }
}

// 192x64 B panel: 1536 chunks, 3/thread @512thr.
__device__ __forceinline__ void stage_b192(const short* __restrict__ g, short* l,
                                           int w, int lane) {
#pragma unroll
  for (int p = 0; p < 3; ++p) {
    int c = (w * 3 + p) * 64 + lane;
    int row = c >> 3;
    int cs = ((c & 7) ^ (row & 7)) * 8;
    glds16(g + (size_t)row * 768 + cs, l + c * 8);
  }
}

__device__ __forceinline__ void bar_fence() {
  asm volatile("" ::: "memory");
  __builtin_amdgcn_s_barrier();
  asm volatile("" ::: "memory");
}

__device__ __forceinline__ void load_a8(const short* base, int wr, int l16, int quad,
                                        bf16x8 (&fa)[4][2]) {
#pragma unroll
  for (int mf = 0; mf < 4; ++mf)
#pragma unroll
    for (int kk = 0; kk < 2; ++kk) {
      int row = wr * 64 + mf * 16 + l16;
      fa[mf][kk] = *(const bf16x8*)&base[row * 64 + ((((kk << 2) + quad) ^ (row & 7)) << 3)];
    }
}

__device__ __forceinline__ void load_b4(const short* base, int rbase, int l16, int quad,
                                        bf16x8 (&fb)[2][2]) {
#pragma unroll
  for (int nf = 0; nf < 2; ++nf)
#pragma unroll
    for (int kk = 0; kk < 2; ++kk) {
      int row = rbase + nf * 16 + l16;
      fb[nf][kk] = *(const bf16x8*)&base[row * 64 + ((((kk << 2) + quad) ^ (row & 7)) << 3)];
    }
}

__device__ __forceinline__ void load_b2(const short* base, int rbase, int l16, int quad,
                                        bf16x8 (&fb)[2]) {
#pragma unroll
  for (int kk = 0; kk < 2; ++kk) {
    int row = rbase + l16;
    fb[kk] = *(const bf16x8*)&base[row * 64 + ((((kk << 2) + quad) ^ (row & 7)) << 3)];
  }
}

__device__ __forceinline__ void mma16(const bf16x8 (&fa)[4][2], const bf16x8 (&fb)[2][2],
                                      f32x4 (&acc)[4][4], int nf0) {
  __builtin_amdgcn_s_setprio(1);
#pragma unroll
  for (int kk = 0; kk < 2; ++kk)
#pragma unroll
    for (int mf = 0; mf < 4; ++mf)
#pragma unroll
      for (int nf = 0; nf < 2; ++nf)
        acc[mf][nf0 + nf] = __builtin_amdgcn_mfma_f32_16x16x32_bf16(
            fa[mf][kk], fb[nf][kk], acc[mf][nf0 + nf], 0, 0, 0);
  __builtin_amdgcn_s_setprio(0);
}

__device__ __forceinline__ void mma16o(const bf16x8 (&fa)[4][2], const bf16x8 (&fb)[2][2],
                                       f32x4 (&acc)[4][3]) {
  __builtin_amdgcn_s_setprio(1);
#pragma unroll
  for (int kk = 0; kk < 2; ++kk)
#pragma unroll
    for (int mf = 0; mf < 4; ++mf)
#pragma unroll
      for (int nf = 0; nf < 2; ++nf)
        acc[mf][nf] = __builtin_amdgcn_mfma_f32_16x16x32_bf16(
            fa[mf][kk], fb[nf][kk], acc[mf][nf], 0, 0, 0);
  __builtin_amdgcn_s_setprio(0);
}

__device__ __forceinline__ void mma8o(const bf16x8 (&fa)[4][2], const bf16x8 (&fb)[2],
                                      f32x4 (&acc)[4][3]) {
  __builtin_amdgcn_s_setprio(1);
#pragma unroll
  for (int kk = 0; kk < 2; ++kk)
#pragma unroll
    for (int mf = 0; mf < 4; ++mf)
      acc[mf][2] = __builtin_amdgcn_mfma_f32_16x16x32_bf16(
          fa[mf][kk], fb[kk], acc[mf][2], 0, 0, 0);
  __builtin_amdgcn_s_setprio(0);
}

// --------------------------------------------------------------------------
// Fused QKV NT GEMM, 128x256 tile, BK=64, depth-3 pipeline (verified r4).
// --------------------------------------------------------------------------
__global__ __launch_bounds__(512, 2) void gemm_qkv(
    const short* __restrict__ xb, const short* __restrict__ wqkv,
    short* __restrict__ q, short* __restrict__ k, short* __restrict__ vt) {
  const int lin = blockIdx.x;
  const int xcd = lin & 7, grp = lin >> 3;       // 576 blocks: 72 per XCD
  const int by = grp >> 3;                       // 0..8 (N tile)
  const int bx = xcd * 8 + (grp & 7);
  const int m0 = bx * 128;
  const int n0g = by * 256;
  const int tid = threadIdx.x;
  const int w = tid >> 6, lane = tid & 63, l16 = lane & 15, quad = lane >> 4;
  const int wr = w >> 2, wc = w & 3;

  __shared__ short lds[3][24576];  // [buf][A:0..8191 | B:8192..24575]

  const short* Asrc = xb + (size_t)m0 * 768;
  const short* Bsrc = wqkv + (size_t)n0g * 768;

  f32x4 acc[4][4];
#pragma unroll
  for (int i = 0; i < 4; ++i)
#pragma unroll
    for (int j = 0; j < 4; ++j) acc[i][j] = (f32x4){0.f, 0.f, 0.f, 0.f};

  stage_half(Asrc, &lds[0][0], w, lane);
  stage_half(Bsrc, &lds[0][8192], w, lane);
  stage_half(Bsrc + 98304, &lds[0][16384], w, lane);
  stage_half(Asrc + 64, &lds[1][0], w, lane);
  stage_half(Bsrc + 64, &lds[1][8192], w, lane);
  stage_half(Bsrc + 98304 + 64, &lds[1][16384], w, lane);
  asm volatile("s_waitcnt vmcnt(6)" ::: "memory");
  bar_fence();

  const int bh = wc >> 1;
  const int rb0 = (wc & 1) * 64;

  bf16x8 fa[4][2], fb0[2][2], fb1[2][2];

#pragma unroll
  for (int t = 0; t < 12; ++t) {
    const int buf = t % 3, nb = (t + 2) % 3;
    const bool pf = (t < 10);
    const short* A = &lds[buf][0];
    const short* Bb = &lds[buf][8192 + bh * 8192];

    // phase A
    load_a8(A, wr, l16, quad, fa);
    load_b4(Bb, rb0, l16, quad, fb0);
    if (pf) {
      stage_half(Asrc + (size_t)(t + 2) * 64, &lds[nb][0], w, lane);
      stage_half(Bsrc + (size_t)(t + 2) * 64, &lds[nb][8192], w, lane);
    }
    bar_fence();
    __builtin_amdgcn_sched_barrier(0);
    mma16(fa, fb0, acc, 0);
    __builtin_amdgcn_sched_barrier(0);
    bar_fence();

    // phase B
    load_b4(Bb, rb0 + 32, l16, quad, fb1);
    if (pf) {
      stage_half(Bsrc + 98304 + (size_t)(t + 2) * 64, &lds[nb][16384], w, lane);
      asm volatile("s_waitcnt vmcnt(6)" ::: "memory");
    } else if (t == 10) {
      asm volatile("s_waitcnt vmcnt(0)" ::: "memory");
    }
    bar_fence();
    __builtin_amdgcn_sched_barrier(0);
    mma16(fa, fb1, acc, 2);
    __builtin_amdgcn_sched_barrier(0);
    bar_fence();
  }

  const int wsel = by / 3;                    // 0:q 1:k 2:v
  const int nl0 = (by % 3) * 256 + wc * 64;
  if (wsel == 2) {
#pragma unroll
    for (int mf = 0; mf < 4; ++mf)
#pragma unroll
      for (int nf = 0; nf < 4; ++nf) {
        int token = m0 + wr * 64 + mf * 16 + quad * 4;
        int nl = nl0 + nf * 16 + l16;
        int bhh = (token >> 10) * 12 + (nl >> 6);
        short tmp[4];
#pragma unroll
        for (int r = 0; r < 4; ++r) tmp[r] = bfbits(acc[mf][nf][r]);
        *(uint2*)(vt + (size_t)bhh * 65536 + (size_t)(nl & 63) * 1024 + (token & 1023)) =
            *(const uint2*)tmp;
      }
  } else {
    short* C = wsel ? k : q;
    const float sc = wsel ? 1.0f : 0.1803368801111244f;  // q: 0.125*log2(e)
#pragma unroll
    for (int mf = 0; mf < 4; ++mf)
#pragma unroll
      for (int nf = 0; nf < 4; ++nf)
#pragma unroll
        for (int r = 0; r < 4; ++r) {
          int row = m0 + wr * 64 + mf * 16 + quad * 4 + r;
          int nl = nl0 + nf * 16 + l16;
          C[(size_t)row * 768 + nl] = bfbits(acc[mf][nf][r] * sc);
        }
  }
}

// --------------------------------------------------------------------------
// attn staging helpers (4 waves, 256 threads; 4 chunks/thread = 16KB tile)
// --------------------------------------------------------------------------
__device__ __forceinline__ void attn_stage_k(const short* __restrict__ kb, int j0,
                                             short* sK, int w, int lane) {
#pragma unroll
  for (int p = 0; p < 4; ++p) {
    int lin = (w * 4 + p) * 64 + lane;
    int row = lin >> 3;
    int cs = ((lin & 7) ^ (row & 7)) * 8;
    glds16(kb + (size_t)(j0 + row) * 768 + cs, &sK[lin * 8]);
  }
}

__device__ __forceinline__ void attn_stage_v(const short* __restrict__ vb, int j0,
                                             short* sVt, int w, int lane) {
#pragma unroll
  for (int p = 0; p < 4; ++p) {
    int lin = (w * 4 + p) * 64 + lane;
    int row = lin >> 4;
    int c = lin & 15;
    int cs = (c ^ (row & 15)) * 8;
    glds16(vb + (size_t)row * 1024 + j0 + cs, &sVt[lin * 8]);
  }
}

// --------------------------------------------------------------------------
// Flash attention, r5: pipelined K/V staging, single-buffer ping-pong.
// K only read in QK phase, V only in PV phase:
//   ... vmcnt(4)[K(j) mine landed] bar | QK(j) reads sK | lgkmcnt(0) bar |
//   issue K(j+1) | softmax (regs)      | vmcnt(4)[V(j)] bar | PV(j) reads sVt |
//   lgkmcnt(0) bar | issue V(j+1) | loop
// Per-wave counted vmcnt BEFORE each barrier => all waves' chunks landed after
// it. Never drains to 0 mid-loop. 32KB LDS, 3 blocks/CU.
// --------------------------------------------------------------------------
__global__ __launch_bounds__(256, 3) void attn_kernel(
    const short* __restrict__ q, const short* __restrict__ k,
    const short* __restrict__ vt, short* __restrict__ vect) {
  const int bh = blockIdx.x % 96;
  const int qt = blockIdx.x / 96;          // 0..7
  const int b = bh / 12, h = bh % 12;
  const int m0 = qt * 128;
  const int tid = threadIdx.x;
  const int w = tid >> 6, lane = tid & 63, l16 = lane & 15, quad = lane >> 4;

  __shared__ short sK[128 * 64];   // K tile; hosts Q (128x64) during prologue
  __shared__ short sVt[64 * 128];  // V^T tile [d][j]

  const size_t base = (size_t)b * 786432 + (size_t)h * 64;
  const short* kb = k + base;
  const short* vb = vt + (size_t)bh * 65536;

  // prologue: stage Q (128x64) into sK, hoist both groups' fragments to regs
#pragma unroll
  for (int p = 0; p < 4; ++p) {
    int lin = (w * 4 + p) * 64 + lane;
    int row = lin >> 3;
    int cs = ((lin & 7) ^ (row & 7)) * 8;
    glds16(q + base + (size_t)(m0 + row) * 768 + cs, &sK[lin * 8]);
  }
  asm volatile("s_waitcnt vmcnt(0)" ::: "memory");
  bar_fence();
  bf16x8 bq[2][2];
#pragma unroll
  for (int g = 0; g < 2; ++g)
#pragma unroll
    for (int kk = 0; kk < 2; ++kk) {
      int row = g * 64 + w * 16 + l16;
      bq[g][kk] = *(const bf16x8*)&sK[row * 64 + (((kk * 4 + quad) ^ (row & 7)) << 3)];
    }
  asm volatile("s_waitcnt lgkmcnt(0)" ::: "memory");
  __builtin_amdgcn_sched_barrier(0);
  bar_fence();

  // stage K(0) then V(0): 4+4 loads/thread in flight
  attn_stage_k(kb, 0, sK, w, lane);
  attn_stage_v(vb, 0, sVt, w, lane);

  f32x4 l4[2];
  l4[0] = (f32x4){0.f, 0.f, 0.f, 0.f};
  l4[1] = (f32x4){0.f, 0.f, 0.f, 0.f};
  f32x4 oacc[2][4];
#pragma unroll
  for (int g = 0; g < 2; ++g)
#pragma unroll
    for (int td = 0; td < 4; ++td) oacc[g][td] = (f32x4){0.f, 0.f, 0.f, 0.f};

  for (int jt = 0; jt < 8; ++jt) {
    const int j0 = jt * 128;
    // my K(jt) chunks landed (V(jt)'s 4 still outstanding); barrier => all waves'
    asm volatile("s_waitcnt vmcnt(4)" ::: "memory");
    bar_fence();

    // QK + softmax per jh half (softmax VALU of jh=0 overlaps QK MFMA of jh=1)
    bf16x4 pb[2][2][4];  // [jh][g][ti]
#pragma unroll
    for (int jh = 0; jh < 2; ++jh) {
      f32x4 s[2][4];
#pragma unroll
      for (int g = 0; g < 2; ++g)
#pragma unroll
        for (int ti = 0; ti < 4; ++ti) s[g][ti] = (f32x4){0.f, 0.f, 0.f, 0.f};
      __builtin_amdgcn_s_setprio(1);
#pragma unroll
      for (int kk = 0; kk < 2; ++kk)
#pragma unroll
        for (int ti = 0; ti < 4; ++ti) {
          int row = jh * 64 + ti * 16 + l16;
          bf16x8 a = *(const bf16x8*)&sK[row * 64 + (((kk * 4 + quad) ^ (row & 7)) << 3)];
          s[0][ti] = __builtin_amdgcn_mfma_f32_16x16x32_bf16(a, bq[0][kk], s[0][ti], 0, 0, 0);
          s[1][ti] = __builtin_amdgcn_mfma_f32_16x16x32_bf16(a, bq[1][kk], s[1][ti], 0, 0, 0);
        }
      __builtin_amdgcn_s_setprio(0);
#pragma unroll
      for (int g = 0; g < 2; ++g)
#pragma unroll
        for (int ti = 0; ti < 4; ++ti) {
          f32x4 e;
          e[0] = fast_exp2(s[g][ti][0]);
          e[1] = fast_exp2(s[g][ti][1]);
          e[2] = fast_exp2(s[g][ti][2]);
          e[3] = fast_exp2(s[g][ti][3]);
          l4[g] += e;
          bf16x4 tb;
          tb[0] = (__bf16)e[0]; tb[1] = (__bf16)e[1];
          tb[2] = (__bf16)e[2]; tb[3] = (__bf16)e[3];
          pb[jh][g][ti] = tb;
        }
    }
    asm volatile("s_waitcnt lgkmcnt(0)" ::: "memory");
    __builtin_amdgcn_sched_barrier(0);
    bar_fence();
    // sK free: issue K(jt+1), lands under PV
    if (jt < 7) attn_stage_k(kb, j0 + 128, sK, w, lane);

    // my V(jt) landed (K(jt+1)'s 4 outstanding if staged)
    if (jt < 7) { asm volatile("s_waitcnt vmcnt(4)" ::: "memory"); }
    else        { asm volatile("s_waitcnt vmcnt(0)" ::: "memory"); }
    bar_fence();

    // PV: O^T += V^T P^T; V A-frag read once feeds both groups
    __builtin_amdgcn_s_setprio(1);
#pragma unroll
    for (int jh = 0; jh < 2; ++jh)
#pragma unroll
      for (int t2 = 0; t2 < 2; ++t2) {
        union { bf16x4 hh[2]; bf16x8 v; } bp0, bp1;
        bp0.hh[0] = pb[jh][0][2 * t2];
        bp0.hh[1] = pb[jh][0][2 * t2 + 1];
        bp1.hh[0] = pb[jh][1][2 * t2];
        bp1.hh[1] = pb[jh][1][2 * t2 + 1];
#pragma unroll
        for (int td = 0; td < 4; ++td) {
          int row = td * 16 + l16;
          int o1 = jh * 64 + t2 * 32 + quad * 4;
          int c1 = o1 >> 3, w1 = o1 & 7;
          int c2 = c1 + 2;
          union { uint2 u[2]; bf16x8 v; } tmp;
          tmp.u[0] = *(const uint2*)&sVt[row * 128 + ((c1 ^ (row & 15)) << 3) + w1];
          tmp.u[1] = *(const uint2*)&sVt[row * 128 + ((c2 ^ (row & 15)) << 3) + w1];
          oacc[0][td] = __builtin_amdgcn_mfma_f32_16x16x32_bf16(tmp.v, bp0.v, oacc[0][td], 0, 0, 0);
          oacc[1][td] = __builtin_amdgcn_mfma_f32_16x16x32_bf16(tmp.v, bp1.v, oacc[1][td], 0, 0, 0);
        }
      }
    __builtin_amdgcn_s_setprio(0);
    asm volatile("s_waitcnt lgkmcnt(0)" ::: "memory");
    __builtin_amdgcn_sched_barrier(0);
    bar_fence();
    // sVt free: issue V(jt+1), lands under next QK
    if (jt < 7) attn_stage_v(vb, j0 + 128, sVt, w, lane);
  }

  // epilogue (writes exactly the q rows this block read -> alias safe)
#pragma unroll
  for (int g = 0; g < 2; ++g) {
    float l = (l4[g][0] + l4[g][1]) + (l4[g][2] + l4[g][3]);
    l += __shfl_xor(l, 16);
    l += __shfl_xor(l, 32);
    float inv = 1.0f / l;
    int i_tok = m0 + g * 64 + w * 16 + l16;
#pragma unroll
    for (int td = 0; td < 4; ++td) {
      short tmp[4];
#pragma unroll
      for (int r = 0; r < 4; ++r) tmp[r] = bfbits(oacc[g][td][r] * inv);
      *(uint2*)(vect + base + (size_t)i_tok * 768 + td * 16 + quad * 4) = *(const uint2*)tmp;
    }
  }
}

// --------------------------------------------------------------------------
// Out projection, r5: 128x192 tile, grid 8x32=256 blocks (exact 1/CU fill),
// 512 thr (8 waves 2Mx4N, per-wave 64x48), depth-3 counted-vmcnt pipeline,
// XCD-local (8 A-panels 1.57MB + Wo 1.2MB < 4MB L2/XCD). LDS 3x40KB.
// Per K-tile: 5 loads/thread (A2+B3); vmcnt(5) per tile boundary.
// --------------------------------------------------------------------------
__global__ __launch_bounds__(512, 2) void gemm_out(
    const short* __restrict__ vect, const short* __restrict__ wob,
    float* __restrict__ out) {
  const int lin = blockIdx.x;
  const int xcd = lin & 7, grp = lin >> 3;   // 256 blocks: 32 per XCD
  const int by = grp >> 3;                   // 0..3
  const int bx = xcd * 8 + (grp & 7);        // 0..63
  const int m0 = bx * 128;
  const int n0g = by * 192;
  const int tid = threadIdx.x;
  const int w = tid >> 6, lane = tid & 63, l16 = lane & 15, quad = lane >> 4;
  const int wr = w >> 2, wc = w & 3;

  __shared__ short lds[3][20480];  // [buf][A:0..8191 | B:8192..20479]

  const short* Asrc = vect + (size_t)m0 * 768;
  const short* Bsrc = wob + (size_t)n0g * 768;

  f32x4 acc[4][3];
#pragma unroll
  for (int i = 0; i < 4; ++i)
#pragma unroll
    for (int j = 0; j < 3; ++j) acc[i][j] = (f32x4){0.f, 0.f, 0.f, 0.f};

  // prologue: tiles 0,1 (5 loads each); vmcnt(5) -> tile0 landed.
  stage_half(Asrc, &lds[0][0], w, lane);
  stage_b192(Bsrc, &lds[0][8192], w, lane);
  stage_half(Asrc + 64, &lds[1][0], w, lane);
  stage_b192(Bsrc + 64, &lds[1][8192], w, lane);
  asm volatile("s_waitcnt vmcnt(5)" ::: "memory");
  bar_fence();

  const int rb0 = wc * 48;
  bf16x8 fa[4][2], fb01[2][2], fb2[2];

#pragma unroll
  for (int t = 0; t < 12; ++t) {
    const int buf = t % 3, nb = (t + 2) % 3;
    const bool pf = (t < 10);
    const short* A = &lds[buf][0];
    const short* Bb = &lds[buf][8192];

    // phase A
    load_a8(A, wr, l16, quad, fa);
    load_b4(Bb, rb0, l16, quad, fb01);
    if (pf) stage_half(Asrc + (size_t)(t + 2) * 64, &lds[nb][0], w, lane);
    bar_fence();
    __builtin_amdgcn_sched_barrier(0);
    mma16o(fa, fb01, acc);
    __builtin_amdgcn_sched_barrier(0);
    bar_fence();

    // phase B
    load_b2(Bb, rb0 + 32, l16, quad, fb2);
    if (pf) {
      stage_b192(Bsrc + (size_t)(t + 2) * 64, &lds[nb][8192], w, lane);
      asm volatile("s_waitcnt vmcnt(5)" ::: "memory");   // tile t+1 fully landed
    } else if (t == 10) {
      asm volatile("s_waitcnt vmcnt(0)" ::: "memory");   // tail
    }
    bar_fence();
    __builtin_amdgcn_sched_barrier(0);
    mma8o(fa, fb2, acc);
    __builtin_amdgcn_sched_barrier(0);
    bar_fence();
  }

#pragma unroll
  for (int mf = 0; mf < 4; ++mf)
#pragma unroll
    for (int nf = 0; nf < 3; ++nf)
#pragma unroll
      for (int r = 0; r < 4; ++r) {
        int row = m0 + wr * 64 + mf * 16 + quad * 4 + r;
        int col = n0g + wc * 48 + nf * 16 + l16;
        out[(size_t)row * 768 + col] = acc[mf][nf][r];
      }
}

// --------------------------------------------------------------------------
extern "C" void kernel_launch(void* const* d_in, const int* in_sizes, int n_in,
                              void* d_out, int out_size, void* d_ws, size_t ws_size,
                              hipStream_t stream) {
  const float* x  = (const float*)d_in[0];
  const float* Wq = (const float*)d_in[1];
  const float* Wk = (const float*)d_in[2];
  const float* Wv = (const float*)d_in[3];
  const float* Wo = (const float*)d_in[4];
  float* out = (float*)d_out;

  const size_t MN = (size_t)8192 * 768;
  short* q    = (short*)d_ws;      // attn output (vect) aliases q
  short* k    = q + MN;
  short* vt   = k + MN;            // per-head transposed V: [96][64][1024]
  short* vect = q;                 // alias (attn writes exactly its own q rows)
  short* wob  = vt + MN;           // bf16 Wo, survives through gemm_out

  short* xb   = (short*)d_out;     // scratch in d_out head (dead before gemm_out)
  short* wqkv = xb + MN;

  convert_kernel<<<1056, 256, 0, stream>>>(x, Wq, Wk, Wv, Wo, xb, wqkv, wob);
  gemm_qkv<<<576, 512, 0, stream>>>(xb, wqkv, q, k, vt);
  attn_kernel<<<768, 256, 0, stream>>>(q, k, vt, vect);
  gemm_out<<<256, 512, 0, stream>>>(vect, wob, out);
}

// Round 6
// 170.528 us; speedup vs baseline: 1.1754x; 1.0327x over previous
//
#include <hip/hip_runtime.h>
#include <hip/hip_bf16.h>
#include <stdint.h>

// MetaAttention: x[8,1024,768] f32, Wq/Wk/Wv/Wo[768,768] f32 -> out[8,1024,768] f32
// Pipeline (4 kernels):
//   convert: x->xb, [Wq;Wk;Wv]->wqkv (d_out head scratch), Wo->wob (d_ws tail).
//   gemm_qkv: fused NT GEMM M=8192 N=2304 K=768. 128x256 tile, BK=64, 512 thr.
//             r6: single 48KB LDS buffer + simple 2-barrier loop at 2 blocks/CU
//             (LB 512,4) — cross-block overlap sets the staging rate (m114/m97:
//             23B/cyc at 3 blk/CU vs 12 at 1 blk with deep pipeline). XCD-local
//             mapping kept (r4). v written in PV-FRAGMENT order (see below).
//   attn: (b,h) x 128 q-rows (grid 768; idx%96=bh). r5 ping-pong staging kept.
//         r6: V stored per-head in PV-fragment order vt[bh][jt][fb][lane][8]
//         -> V-stage is a linear 16KB copy; PV reads ONE conflict-free
//         ds_read_b128/frag (was 2x b64 at 4-way conflict, 3.1M cycles).
//   gemm_out: 128x192 tile, grid 256 (1/CU), depth-3 counted vmcnt (r5).
// d_ws (bf16): q/vect | k | vt | wob.

typedef __bf16 bf16x8 __attribute__((ext_vector_type(8)));
typedef __bf16 bf16x4 __attribute__((ext_vector_type(4)));
typedef float f32x4 __attribute__((ext_vector_type(4)));

#define GAS __attribute__((address_space(1)))
#define LAS __attribute__((address_space(3)))

__device__ __forceinline__ void glds16(const short* gp, short* lp) {
  __builtin_amdgcn_global_load_lds((const GAS void*)gp, (LAS void*)lp, 16, 0, 0);
}

__device__ __forceinline__ float fast_exp2(float x) {
#if __has_builtin(__builtin_amdgcn_exp2f)
  return __builtin_amdgcn_exp2f(x);
#else
  return __expf(x * 0.6931471805599453f);
#endif
}

__device__ __forceinline__ short bfbits(float f) {
  __bf16 b = (__bf16)f;                  // fptrunc RNE -> HW cvt
  union { __bf16 b; short s; } cv; cv.b = b;
  return cv.s;
}

__device__ __forceinline__ void stage8_f32(const float* __restrict__ src, short* dst) {
  float4 f0 = ((const float4*)src)[0];
  float4 f1 = ((const float4*)src)[1];
  bf16x8 t;
  t[0] = (__bf16)f0.x; t[1] = (__bf16)f0.y; t[2] = (__bf16)f0.z; t[3] = (__bf16)f0.w;
  t[4] = (__bf16)f1.x; t[5] = (__bf16)f1.y; t[6] = (__bf16)f1.z; t[7] = (__bf16)f1.w;
  *(bf16x8*)dst = t;
}

// --------------------------------------------------------------------------
// fp32 -> bf16 bulk conversion, flat exact grid: 1056 blocks x 1024 units.
// --------------------------------------------------------------------------
__global__ __launch_bounds__(256) void convert_kernel(
    const float* __restrict__ x, const float* __restrict__ Wq,
    const float* __restrict__ Wk, const float* __restrict__ Wv,
    const float* __restrict__ Wo,
    short* __restrict__ xb, short* __restrict__ wqkv, short* __restrict__ wob) {
  int u0 = blockIdx.x * 1024 + threadIdx.x;
#pragma unroll
  for (int i = 0; i < 4; ++i) {
    int u = u0 + i * 256;
    const float* src; short* dst;
    if (u < 786432) { src = x + (size_t)u * 8; dst = xb + (size_t)u * 8; }
    else if (u < 1007616) {
      int r = u - 786432;
      int wsel = r / 73728, off = r % 73728;
      const float* W = (wsel == 0) ? Wq : (wsel == 1) ? Wk : Wv;
      src = W + (size_t)off * 8;
      dst = wqkv + (size_t)r * 8;
    } else {
      int r = u - 1007616;
      src = Wo + (size_t)r * 8; dst = wob + (size_t)r * 8;
    }
    stage8_f32(src, dst);
  }
}

// --------------------------------------------------------------------------
// shared GEMM helpers
// --------------------------------------------------------------------------
__device__ __forceinline__ void stage_half(const short* __restrict__ g, short* l,
                                           int w, int lane) {
#pragma unroll
  for (int p = 0; p < 2; ++p) {
    int c = (w * 2 + p) * 64 + lane;
    int row = c >> 3;
    int cs = ((c & 7) ^ (row & 7)) * 8;
    glds16(g + (size_t)row * 768 + cs, l + c * 8);
  }
}

// 192x64 B panel: 1536 chunks, 3/thread @512thr.
__device__ __forceinline__ void stage_b192(const short* __restrict__ g, short* l,
                                           int w, int lane) {
#pragma unroll
  for (int p = 0; p < 3; ++p) {
    int c = (w * 3 + p) * 64 + lane;
    int row = c >> 3;
    int cs = ((c & 7) ^ (row & 7)) * 8;
    glds16(g + (size_t)row * 768 + cs, l + c * 8);
  }
}

__device__ __forceinline__ void bar_fence() {
  asm volatile("" ::: "memory");
  __builtin_amdgcn_s_barrier();
  asm volatile("" ::: "memory");
}

__device__ __forceinline__ void load_a8(const short* base, int wr, int l16, int quad,
                                        bf16x8 (&fa)[4][2]) {
#pragma unroll
  for (int mf = 0; mf < 4; ++mf)
#pragma unroll
    for (int kk = 0; kk < 2; ++kk) {
      int row = wr * 64 + mf * 16 + l16;
      fa[mf][kk] = *(const bf16x8*)&base[row * 64 + ((((kk << 2) + quad) ^ (row & 7)) << 3)];
    }
}

__device__ __forceinline__ void load_b4(const short* base, int rbase, int l16, int quad,
                                        bf16x8 (&fb)[2][2]) {
#pragma unroll
  for (int nf = 0; nf < 2; ++nf)
#pragma unroll
    for (int kk = 0; kk < 2; ++kk) {
      int row = rbase + nf * 16 + l16;
      fb[nf][kk] = *(const bf16x8*)&base[row * 64 + ((((kk << 2) + quad) ^ (row & 7)) << 3)];
    }
}

__device__ __forceinline__ void load_b2(const short* base, int rbase, int l16, int quad,
                                        bf16x8 (&fb)[2]) {
#pragma unroll
  for (int kk = 0; kk < 2; ++kk) {
    int row = rbase + l16;
    fb[kk] = *(const bf16x8*)&base[row * 64 + ((((kk << 2) + quad) ^ (row & 7)) << 3)];
  }
}

__device__ __forceinline__ void mma16(const bf16x8 (&fa)[4][2], const bf16x8 (&fb)[2][2],
                                      f32x4 (&acc)[4][4], int nf0) {
  __builtin_amdgcn_s_setprio(1);
#pragma unroll
  for (int kk = 0; kk < 2; ++kk)
#pragma unroll
    for (int mf = 0; mf < 4; ++mf)
#pragma unroll
      for (int nf = 0; nf < 2; ++nf)
        acc[mf][nf0 + nf] = __builtin_amdgcn_mfma_f32_16x16x32_bf16(
            fa[mf][kk], fb[nf][kk], acc[mf][nf0 + nf], 0, 0, 0);
  __builtin_amdgcn_s_setprio(0);
}

__device__ __forceinline__ void mma16o(const bf16x8 (&fa)[4][2], const bf16x8 (&fb)[2][2],
                                       f32x4 (&acc)[4][3]) {
  __builtin_amdgcn_s_setprio(1);
#pragma unroll
  for (int kk = 0; kk < 2; ++kk)
#pragma unroll
    for (int mf = 0; mf < 4; ++mf)
#pragma unroll
      for (int nf = 0; nf < 2; ++nf)
        acc[mf][nf] = __builtin_amdgcn_mfma_f32_16x16x32_bf16(
            fa[mf][kk], fb[nf][kk], acc[mf][nf], 0, 0, 0);
  __builtin_amdgcn_s_setprio(0);
}

__device__ __forceinline__ void mma8o(const bf16x8 (&fa)[4][2], const bf16x8 (&fb)[2],
                                      f32x4 (&acc)[4][3]) {
  __builtin_amdgcn_s_setprio(1);
#pragma unroll
  for (int kk = 0; kk < 2; ++kk)
#pragma unroll
    for (int mf = 0; mf < 4; ++mf)
      acc[mf][2] = __builtin_amdgcn_mfma_f32_16x16x32_bf16(
          fa[mf][kk], fb[kk], acc[mf][2], 0, 0, 0);
  __builtin_amdgcn_s_setprio(0);
}

// --------------------------------------------------------------------------
// Fused QKV NT GEMM, 128x256 tile, BK=64.
// r6: single 48KB buffer, simple 2-barrier loop, 2 blocks/CU (LB 512,4) —
// cross-block overlap hides staging latency (m114); the depth-3 147KB version
// pinned occupancy at 1 block/CU and plateaued at 12B/cyc/CU delivery.
// XCD-local mapping (r4): each XCD owns 8 bx x all 9 by.
// v epilogue writes PV-fragment order (see attn): for output element
// (token,d): jt=(token>>7)&7, to1=token&127 -> jh=to1>>6, t2=(to1>>5)&1,
// kk=(to1>>4)&1, quadv=(to1>>2)&3, r=to1&3; fb=(jh*2+t2)*4+(d>>4);
// lane=(d&15)+16*quadv; offset = bh*65536 + jt*8192 + fb*512 + lane*8 + kk*4 + r.
// For this wave: jh=wr, t2=mf>>1, kk=mf&1, quadv=quad, d=nf*16+l16.
// --------------------------------------------------------------------------
__global__ __launch_bounds__(512, 4) void gemm_qkv(
    const short* __restrict__ xb, const short* __restrict__ wqkv,
    short* __restrict__ q, short* __restrict__ k, short* __restrict__ vt) {
  const int lin = blockIdx.x;
  const int xcd = lin & 7, grp = lin >> 3;       // 576 blocks: 72 per XCD
  const int by = grp >> 3;                       // 0..8 (N tile)
  const int bx = xcd * 8 + (grp & 7);
  const int m0 = bx * 128;
  const int n0g = by * 256;
  const int tid = threadIdx.x;
  const int w = tid >> 6, lane = tid & 63, l16 = lane & 15, quad = lane >> 4;
  const int wr = w >> 2, wc = w & 3;

  __shared__ short sA[8192];    // 128x64
  __shared__ short sB[16384];   // 256x64

  const short* Asrc = xb + (size_t)m0 * 768;
  const short* Bsrc = wqkv + (size_t)n0g * 768;

  f32x4 acc[4][4];
#pragma unroll
  for (int i = 0; i < 4; ++i)
#pragma unroll
    for (int j = 0; j < 4; ++j) acc[i][j] = (f32x4){0.f, 0.f, 0.f, 0.f};

  const int bh = wc >> 1;          // which 128-row half of B holds this wave's band
  const int rb0 = (wc & 1) * 64;   // row base within that half

  for (int t = 0; t < 12; ++t) {
    __syncthreads();               // prior tile's LDS reads retired
    stage_half(Asrc + (size_t)t * 64, sA, w, lane);
    stage_half(Bsrc + (size_t)t * 64, sB, w, lane);
    stage_half(Bsrc + 98304 + (size_t)t * 64, &sB[8192], w, lane);
    __syncthreads();               // compiler drains vmcnt(0): tile landed
    bf16x8 fa[4][2], fb0[2][2], fb1[2][2];
    load_a8(sA, wr, l16, quad, fa);
    load_b4(&sB[bh * 8192], rb0, l16, quad, fb0);
    mma16(fa, fb0, acc, 0);
    load_b4(&sB[bh * 8192], rb0 + 32, l16, quad, fb1);
    mma16(fa, fb1, acc, 2);
  }

  const int wsel = by / 3;                    // 0:q 1:k 2:v
  const int nl0 = (by % 3) * 256 + wc * 64;
  if (wsel == 2) {
#pragma unroll
    for (int mf = 0; mf < 4; ++mf)
#pragma unroll
      for (int nf = 0; nf < 4; ++nf) {
        int token = m0 + wr * 64 + mf * 16 + quad * 4;  // +r contiguous
        int nl = nl0 + nf * 16 + l16;
        int bhh = (token >> 10) * 12 + (nl >> 6);
        int jt = (token >> 7) & 7;
        int fb = (wr * 2 + (mf >> 1)) * 4 + nf;         // (jh*2+t2)*4 + d>>4
        short tmp[4];
#pragma unroll
        for (int r = 0; r < 4; ++r) tmp[r] = bfbits(acc[mf][nf][r]);
        *(uint2*)(vt + (size_t)bhh * 65536 + jt * 8192 + fb * 512 +
                  (l16 + 16 * quad) * 8 + (mf & 1) * 4) = *(const uint2*)tmp;
      }
  } else {
    short* C = wsel ? k : q;
    const float sc = wsel ? 1.0f : 0.1803368801111244f;  // q: 0.125*log2(e)
#pragma unroll
    for (int mf = 0; mf < 4; ++mf)
#pragma unroll
      for (int nf = 0; nf < 4; ++nf)
#pragma unroll
        for (int r = 0; r < 4; ++r) {
          int row = m0 + wr * 64 + mf * 16 + quad * 4 + r;
          int nl = nl0 + nf * 16 + l16;
          C[(size_t)row * 768 + nl] = bfbits(acc[mf][nf][r] * sc);
        }
  }
}

// --------------------------------------------------------------------------
// attn staging helpers (4 waves, 256 threads; 4 chunks/thread = 16KB tile)
// --------------------------------------------------------------------------
__device__ __forceinline__ void attn_stage_k(const short* __restrict__ kb, int j0,
                                             short* sK, int w, int lane) {
#pragma unroll
  for (int p = 0; p < 4; ++p) {
    int lin = (w * 4 + p) * 64 + lane;
    int row = lin >> 3;
    int cs = ((lin & 7) ^ (row & 7)) * 8;
    glds16(kb + (size_t)(j0 + row) * 768 + cs, &sK[lin * 8]);
  }
}

// V tile jt: LINEAR 16KB copy (global already in PV-fragment order).
__device__ __forceinline__ void attn_stage_v(const short* __restrict__ vb, int jt,
                                             short* sVt, int w, int lane) {
#pragma unroll
  for (int p = 0; p < 4; ++p) {
    int c = (w * 4 + p) * 64 + lane;
    glds16(vb + (size_t)jt * 8192 + (size_t)c * 8, &sVt[c * 8]);
  }
}

// --------------------------------------------------------------------------
// Flash attention, r5 ping-pong sync + r6 fragment-order V.
//   vmcnt(4)[K(j) mine] bar | QK(j) reads sK | lgkmcnt(0) bar | issue K(j+1) |
//   softmax (regs) | vmcnt(4)[V(j)] bar | PV(j): ds_read_b128 frag (conflict-
//   free, lane*16 consecutive) | lgkmcnt(0) bar | issue V(j+1) | loop.
// 32KB LDS, 3 blocks/CU.
// --------------------------------------------------------------------------
__global__ __launch_bounds__(256, 3) void attn_kernel(
    const short* __restrict__ q, const short* __restrict__ k,
    const short* __restrict__ vt, short* __restrict__ vect) {
  const int bh = blockIdx.x % 96;
  const int qt = blockIdx.x / 96;          // 0..7
  const int b = bh / 12, h = bh % 12;
  const int m0 = qt * 128;
  const int tid = threadIdx.x;
  const int w = tid >> 6, lane = tid & 63, l16 = lane & 15, quad = lane >> 4;

  __shared__ short sK[128 * 64];   // K tile; hosts Q (128x64) during prologue
  __shared__ short sVt[64 * 128];  // V tile jt in fragment order [fb][lane][8]

  const size_t base = (size_t)b * 786432 + (size_t)h * 64;
  const short* kb = k + base;
  const short* vb = vt + (size_t)bh * 65536;

  // prologue: stage Q (128x64) into sK, hoist both groups' fragments to regs
#pragma unroll
  for (int p = 0; p < 4; ++p) {
    int lin = (w * 4 + p) * 64 + lane;
    int row = lin >> 3;
    int cs = ((lin & 7) ^ (row & 7)) * 8;
    glds16(q + base + (size_t)(m0 + row) * 768 + cs, &sK[lin * 8]);
  }
  asm volatile("s_waitcnt vmcnt(0)" ::: "memory");
  bar_fence();
  bf16x8 bq[2][2];
#pragma unroll
  for (int g = 0; g < 2; ++g)
#pragma unroll
    for (int kk = 0; kk < 2; ++kk) {
      int row = g * 64 + w * 16 + l16;
      bq[g][kk] = *(const bf16x8*)&sK[row * 64 + (((kk * 4 + quad) ^ (row & 7)) << 3)];
    }
  asm volatile("s_waitcnt lgkmcnt(0)" ::: "memory");
  __builtin_amdgcn_sched_barrier(0);
  bar_fence();

  // stage K(0) then V(0): 4+4 loads/thread in flight
  attn_stage_k(kb, 0, sK, w, lane);
  attn_stage_v(vb, 0, sVt, w, lane);

  f32x4 l4[2];
  l4[0] = (f32x4){0.f, 0.f, 0.f, 0.f};
  l4[1] = (f32x4){0.f, 0.f, 0.f, 0.f};
  f32x4 oacc[2][4];
#pragma unroll
  for (int g = 0; g < 2; ++g)
#pragma unroll
    for (int td = 0; td < 4; ++td) oacc[g][td] = (f32x4){0.f, 0.f, 0.f, 0.f};

  for (int jt = 0; jt < 8; ++jt) {
    // my K(jt) chunks landed (V(jt)'s 4 still outstanding); barrier => all waves'
    asm volatile("s_waitcnt vmcnt(4)" ::: "memory");
    bar_fence();

    // QK + softmax per jh half (softmax VALU of jh=0 overlaps QK MFMA of jh=1)
    bf16x4 pb[2][2][4];  // [jh][g][ti]
#pragma unroll
    for (int jh = 0; jh < 2; ++jh) {
      f32x4 s[2][4];
#pragma unroll
      for (int g = 0; g < 2; ++g)
#pragma unroll
        for (int ti = 0; ti < 4; ++ti) s[g][ti] = (f32x4){0.f, 0.f, 0.f, 0.f};
      __builtin_amdgcn_s_setprio(1);
#pragma unroll
      for (int kk = 0; kk < 2; ++kk)
#pragma unroll
        for (int ti = 0; ti < 4; ++ti) {
          int row = jh * 64 + ti * 16 + l16;
          bf16x8 a = *(const bf16x8*)&sK[row * 64 + (((kk * 4 + quad) ^ (row & 7)) << 3)];
          s[0][ti] = __builtin_amdgcn_mfma_f32_16x16x32_bf16(a, bq[0][kk], s[0][ti], 0, 0, 0);
          s[1][ti] = __builtin_amdgcn_mfma_f32_16x16x32_bf16(a, bq[1][kk], s[1][ti], 0, 0, 0);
        }
      __builtin_amdgcn_s_setprio(0);
#pragma unroll
      for (int g = 0; g < 2; ++g)
#pragma unroll
        for (int ti = 0; ti < 4; ++ti) {
          f32x4 e;
          e[0] = fast_exp2(s[g][ti][0]);
          e[1] = fast_exp2(s[g][ti][1]);
          e[2] = fast_exp2(s[g][ti][2]);
          e[3] = fast_exp2(s[g][ti][3]);
          l4[g] += e;
          bf16x4 tb;
          tb[0] = (__bf16)e[0]; tb[1] = (__bf16)e[1];
          tb[2] = (__bf16)e[2]; tb[3] = (__bf16)e[3];
          pb[jh][g][ti] = tb;
        }
    }
    asm volatile("s_waitcnt lgkmcnt(0)" ::: "memory");
    __builtin_amdgcn_sched_barrier(0);
    bar_fence();
    // sK free: issue K(jt+1), lands under PV
    if (jt < 7) attn_stage_k(kb, (jt + 1) * 128, sK, w, lane);

    // my V(jt) landed (K(jt+1)'s 4 outstanding if staged)
    if (jt < 7) { asm volatile("s_waitcnt vmcnt(4)" ::: "memory"); }
    else        { asm volatile("s_waitcnt vmcnt(0)" ::: "memory"); }
    bar_fence();

    // PV: O^T += V^T P^T; fragment-order V: one b128 per (jh,t2,td), lane*16
    // consecutive -> conflict-free; frag feeds both q-row groups.
    __builtin_amdgcn_s_setprio(1);
#pragma unroll
    for (int jh = 0; jh < 2; ++jh)
#pragma unroll
      for (int t2 = 0; t2 < 2; ++t2) {
        union { bf16x4 hh[2]; bf16x8 v; } bp0, bp1;
        bp0.hh[0] = pb[jh][0][2 * t2];
        bp0.hh[1] = pb[jh][0][2 * t2 + 1];
        bp1.hh[0] = pb[jh][1][2 * t2];
        bp1.hh[1] = pb[jh][1][2 * t2 + 1];
        const int fb = (jh * 2 + t2) * 4;
#pragma unroll
        for (int td = 0; td < 4; ++td) {
          bf16x8 av = *(const bf16x8*)&sVt[(fb + td) * 512 + lane * 8];
          oacc[0][td] = __builtin_amdgcn_mfma_f32_16x16x32_bf16(av, bp0.v, oacc[0][td], 0, 0, 0);
          oacc[1][td] = __builtin_amdgcn_mfma_f32_16x16x32_bf16(av, bp1.v, oacc[1][td], 0, 0, 0);
        }
      }
    __builtin_amdgcn_s_setprio(0);
    asm volatile("s_waitcnt lgkmcnt(0)" ::: "memory");
    __builtin_amdgcn_sched_barrier(0);
    bar_fence();
    // sVt free: issue V(jt+1), lands under next QK
    if (jt < 7) attn_stage_v(vb, jt + 1, sVt, w, lane);
  }

  // epilogue (writes exactly the q rows this block read -> alias safe)
#pragma unroll
  for (int g = 0; g < 2; ++g) {
    float l = (l4[g][0] + l4[g][1]) + (l4[g][2] + l4[g][3]);
    l += __shfl_xor(l, 16);
    l += __shfl_xor(l, 32);
    float inv = 1.0f / l;
    int i_tok = m0 + g * 64 + w * 16 + l16;
#pragma unroll
    for (int td = 0; td < 4; ++td) {
      short tmp[4];
#pragma unroll
      for (int r = 0; r < 4; ++r) tmp[r] = bfbits(oacc[g][td][r] * inv);
      *(uint2*)(vect + base + (size_t)i_tok * 768 + td * 16 + quad * 4) = *(const uint2*)tmp;
    }
  }
}

// --------------------------------------------------------------------------
// Out projection: 128x192 tile, grid 256 (exact 1/CU fill), 512 thr,
// depth-3 counted-vmcnt pipeline, XCD-local (r5, unchanged).
// --------------------------------------------------------------------------
__global__ __launch_bounds__(512, 2) void gemm_out(
    const short* __restrict__ vect, const short* __restrict__ wob,
    float* __restrict__ out) {
  const int lin = blockIdx.x;
  const int xcd = lin & 7, grp = lin >> 3;   // 256 blocks: 32 per XCD
  const int by = grp >> 3;                   // 0..3
  const int bx = xcd * 8 + (grp & 7);        // 0..63
  const int m0 = bx * 128;
  const int n0g = by * 192;
  const int tid = threadIdx.x;
  const int w = tid >> 6, lane = tid & 63, l16 = lane & 15, quad = lane >> 4;
  const int wr = w >> 2, wc = w & 3;

  __shared__ short lds[3][20480];  // [buf][A:0..8191 | B:8192..20479]

  const short* Asrc = vect + (size_t)m0 * 768;
  const short* Bsrc = wob + (size_t)n0g * 768;

  f32x4 acc[4][3];
#pragma unroll
  for (int i = 0; i < 4; ++i)
#pragma unroll
    for (int j = 0; j < 3; ++j) acc[i][j] = (f32x4){0.f, 0.f, 0.f, 0.f};

  // prologue: tiles 0,1 (5 loads each); vmcnt(5) -> tile0 landed.
  stage_half(Asrc, &lds[0][0], w, lane);
  stage_b192(Bsrc, &lds[0][8192], w, lane);
  stage_half(Asrc + 64, &lds[1][0], w, lane);
  stage_b192(Bsrc + 64, &lds[1][8192], w, lane);
  asm volatile("s_waitcnt vmcnt(5)" ::: "memory");
  bar_fence();

  const int rb0 = wc * 48;
  bf16x8 fa[4][2], fb01[2][2], fb2[2];

#pragma unroll
  for (int t = 0; t < 12; ++t) {
    const int buf = t % 3, nb = (t + 2) % 3;
    const bool pf = (t < 10);
    const short* A = &lds[buf][0];
    const short* Bb = &lds[buf][8192];

    // phase A
    load_a8(A, wr, l16, quad, fa);
    load_b4(Bb, rb0, l16, quad, fb01);
    if (pf) stage_half(Asrc + (size_t)(t + 2) * 64, &lds[nb][0], w, lane);
    bar_fence();
    __builtin_amdgcn_sched_barrier(0);
    mma16o(fa, fb01, acc);
    __builtin_amdgcn_sched_barrier(0);
    bar_fence();

    // phase B
    load_b2(Bb, rb0 + 32, l16, quad, fb2);
    if (pf) {
      stage_b192(Bsrc + (size_t)(t + 2) * 64, &lds[nb][8192], w, lane);
      asm volatile("s_waitcnt vmcnt(5)" ::: "memory");   // tile t+1 fully landed
    } else if (t == 10) {
      asm volatile("s_waitcnt vmcnt(0)" ::: "memory");   // tail
    }
    bar_fence();
    __builtin_amdgcn_sched_barrier(0);
    mma8o(fa, fb2, acc);
    __builtin_amdgcn_sched_barrier(0);
    bar_fence();
  }

#pragma unroll
  for (int mf = 0; mf < 4; ++mf)
#pragma unroll
    for (int nf = 0; nf < 3; ++nf)
#pragma unroll
      for (int r = 0; r < 4; ++r) {
        int row = m0 + wr * 64 + mf * 16 + quad * 4 + r;
        int col = n0g + wc * 48 + nf * 16 + l16;
        out[(size_t)row * 768 + col] = acc[mf][nf][r];
      }
}

// --------------------------------------------------------------------------
extern "C" void kernel_launch(void* const* d_in, const int* in_sizes, int n_in,
                              void* d_out, int out_size, void* d_ws, size_t ws_size,
                              hipStream_t stream) {
  const float* x  = (const float*)d_in[0];
  const float* Wq = (const float*)d_in[1];
  const float* Wk = (const float*)d_in[2];
  const float* Wv = (const float*)d_in[3];
  const float* Wo = (const float*)d_in[4];
  float* out = (float*)d_out;

  const size_t MN = (size_t)8192 * 768;
  short* q    = (short*)d_ws;      // attn output (vect) aliases q
  short* k    = q + MN;
  short* vt   = k + MN;            // per-head fragment-order V: [96][8][16][64][8]
  short* vect = q;                 // alias (attn writes exactly its own q rows)
  short* wob  = vt + MN;           // bf16 Wo, survives through gemm_out

  short* xb   = (short*)d_out;     // scratch in d_out head (dead before gemm_out)
  short* wqkv = xb + MN;

  convert_kernel<<<1056, 256, 0, stream>>>(x, Wq, Wk, Wv, Wo, xb, wqkv, wob);
  gemm_qkv<<<576, 512, 0, stream>>>(xb, wqkv, q, k, vt);
  attn_kernel<<<768, 256, 0, stream>>>(q, k, vt, vect);
  gemm_out<<<256, 512, 0, stream>>>(vect, wob, out);
}